// Round 17
// baseline (201.459 us; speedup 1.0000x reference)
//
#include <hip/hip_runtime.h>
#include <hip/hip_bf16.h>

#define B_ 2
#define S_ 2048
#define E_ 1024
#define H_ 16
#define D_ 64
#define M_ 4096  // B_*S_

typedef __bf16 bf16_t;
typedef bf16_t bf16x8 __attribute__((ext_vector_type(8)));
typedef float f32x4 __attribute__((ext_vector_type(4)));
typedef unsigned int u32;

__device__ __forceinline__ f32x4 mfma16(bf16x8 a, bf16x8 b, f32x4 c) {
    return __builtin_amdgcn_mfma_f32_16x16x32_bf16(a, b, c, 0, 0, 0);
}
__device__ __forceinline__ unsigned short f2bf(float f) {
    unsigned int u = __float_as_uint(f);
    unsigned int r = (u + 0x7fffu + ((u >> 16) & 1u)) >> 16;
    return (unsigned short)r;
}
__device__ __forceinline__ float bf2f(unsigned short s) {
    return __uint_as_float(((unsigned int)s) << 16);
}
// pack two f32 -> dword of 2 bf16 (src0 -> low half), RTNE
__device__ __forceinline__ u32 cvt_pk_bf16(float lo, float hi) {
    u32 r;
    asm("v_cvt_pk_bf16_f32 %0, %1, %2" : "=v"(r) : "v"(lo), "v"(hi));
    return r;
}
// order-preserving float<->uint for atomic min/max
__device__ __forceinline__ unsigned int fenc(float x) {
    unsigned int u = __float_as_uint(x);
    return (u & 0x80000000u) ? ~u : (u | 0x80000000u);
}
__device__ __forceinline__ float fdec(unsigned int u) {
    return __uint_as_float((u & 0x80000000u) ? (u ^ 0x80000000u) : ~u);
}
// async global->LDS DMA, 16B per lane; LDS dest = wave-uniform base + lane*16
__device__ __forceinline__ void gload16(const void* g, void* l) {
    __builtin_amdgcn_global_load_lds((const __attribute__((address_space(1))) u32*)g,
                                     (__attribute__((address_space(3))) u32*)l, 16, 0, 0);
}

__global__ void k_init(unsigned int* mm) {
    int t = threadIdx.x;
    if (t < 2) { mm[t * 2] = 0xFFFFFFFFu; mm[t * 2 + 1] = 0u; }
}

__global__ __launch_bounds__(256) void k_cast(const float* __restrict__ src,
                                              unsigned short* __restrict__ dst, int n8) {
    int i = blockIdx.x * 256 + threadIdx.x;
    if (i >= n8) return;
    const float4* s4 = (const float4*)src;
    float4 a = s4[2 * i], c = s4[2 * i + 1];
    uint4 o;
    o.x = cvt_pk_bf16(a.x, a.y);
    o.y = cvt_pk_bf16(a.z, a.w);
    o.z = cvt_pk_bf16(c.x, c.y);
    o.w = cvt_pk_bf16(c.z, c.w);
    ((uint4*)dst)[i] = o;
}

// C[m][n] = sum_k A[m][k]*B[n][k] + bias[n].  A:[4096][1024], B:[1024][1024] (row=n, contiguous k), bf16.
// 64x64 tile, 4 waves (32x32 each), BK=64: grid (64,16)=1024 blocks -> 4 independent
// blocks/CU (LDS 32 KB) - the attn-proven occupancy regime. K-ring PHASE STAGGER
// (ph = (bx + 7*by) & 15, accumulation is order-independent) decorrelates co-resident
// blocks' stage/compute phases (anti-convoy; the lever r14 lacked). r13 skeleton:
// global_load_lds(16B) double-buffered, counted vmcnt(4), 2 barriers/step.
// Swizzle: pre-swizzled GLOBAL source (chunk ^= row&7), same XOR on ds_read; LDS linear.
// MODE 0: write bf16 v [b][h][s][d] + transposed vt [b][h][d][s] + per-batch min/max atomics.
// MODE 1: write fp32 outf[m][n].
template <int MODE>
__global__ __launch_bounds__(256, 4) void k_gemm(const unsigned short* __restrict__ A,
                                                 const unsigned short* __restrict__ Bm,
                                                 const float* __restrict__ bias,
                                                 unsigned short* __restrict__ outb,
                                                 unsigned short* __restrict__ vtb,
                                                 float* __restrict__ outf,
                                                 unsigned int* __restrict__ mm) {
    __shared__ __align__(16) unsigned short Asm[2][4096];  // [buf][64 rows x 64 shorts]
    __shared__ __align__(16) unsigned short Bsm[2][4096];  // [buf][64 rows x 64 shorts]
    const int K = 1024;
    int tid = threadIdx.x, lane = tid & 63, wv = tid >> 6;
    int wm = wv >> 1, wn = wv & 1;   // 2x2 wave grid: 32x32 each
    int m0 = blockIdx.x * 64, n0 = blockIdx.y * 64;
    int ph = (blockIdx.x + 7 * blockIdx.y) & 15;  // K-ring start phase (anti-convoy)
    int lrow = lane & 15, lgrp = lane >> 4, sw = lane & 7;
    int r8 = lane >> 3, ch = lane & 7;
    // pre-swizzled global sources: lane covers (row = i*32 + wv*8 + r8, 16B chunk = ch ^ r8)
    const unsigned short* Ag = A + (size_t)(m0 + wv * 8 + r8) * K + ((ch ^ r8) << 3);
    const unsigned short* Bg = Bm + (size_t)(n0 + wv * 8 + r8) * K + ((ch ^ r8) << 3);

#define STAGE(buf, kk)                                                                     \
    {                                                                                      \
        _Pragma("unroll") for (int i = 0; i < 2; ++i)                                      \
            gload16(Ag + (size_t)(i * 32) * K + (kk), &Asm[buf][(i * 32 + wv * 8) * 64]);  \
        _Pragma("unroll") for (int i = 0; i < 2; ++i)                                      \
            gload16(Bg + (size_t)(i * 32) * K + (kk), &Bsm[buf][(i * 32 + wv * 8) * 64]);  \
    }
#define COMPUTE(buf)                                                                        \
    {                                                                                       \
        _Pragma("unroll") for (int kh = 0; kh < 2; ++kh) {                                  \
            int cp = (((kh << 2) | lgrp) ^ sw) << 3;                                        \
            bf16x8 af[2], bfr[2];                                                           \
            _Pragma("unroll") for (int mt = 0; mt < 2; ++mt)                                \
                af[mt] = *(const bf16x8*)&Asm[buf][(wm * 32 + mt * 16 + lrow) * 64 + cp];   \
            _Pragma("unroll") for (int nt = 0; nt < 2; ++nt)                                \
                bfr[nt] = *(const bf16x8*)&Bsm[buf][(wn * 32 + nt * 16 + lrow) * 64 + cp];  \
            _Pragma("unroll") for (int mt = 0; mt < 2; ++mt)                                \
                _Pragma("unroll") for (int nt = 0; nt < 2; ++nt)                            \
                    acc[mt][nt] = mfma16(af[mt], bfr[nt], acc[mt][nt]);                     \
        }                                                                                   \
    }

    f32x4 acc[2][2];
#pragma unroll
    for (int i = 0; i < 2; ++i)
#pragma unroll
        for (int j = 0; j < 2; ++j) acc[i][j] = (f32x4){0.f, 0.f, 0.f, 0.f};

    STAGE(0, ph * 64);
    STAGE(1, ((ph + 1) & 15) * 64);
    for (int t = 0; t < 15; ++t) {
        asm volatile("s_waitcnt vmcnt(4)" ::: "memory");  // tile t landed; t+1's 4 in flight
        __builtin_amdgcn_s_barrier();
        __builtin_amdgcn_sched_barrier(0);
        __builtin_amdgcn_s_setprio(1);
        COMPUTE(t & 1);
        __builtin_amdgcn_s_setprio(0);
        asm volatile("s_waitcnt lgkmcnt(0)" ::: "memory");  // my reads done before overwrite
        __builtin_amdgcn_s_barrier();
        __builtin_amdgcn_sched_barrier(0);
        if (t < 14) STAGE(t & 1, ((t + 2 + ph) & 15) * 64);
    }
    asm volatile("s_waitcnt vmcnt(0)" ::: "memory");
    __builtin_amdgcn_s_barrier();
    __builtin_amdgcn_sched_barrier(0);
    COMPUTE(1);
#undef STAGE
#undef COMPUTE

    float vmin = 1e30f, vmax = -1e30f;
#pragma unroll
    for (int nt = 0; nt < 2; ++nt) {
        int ncol = n0 + wn * 32 + nt * 16 + lrow;
        float bs = bias[ncol];
#pragma unroll
        for (int mt = 0; mt < 2; ++mt) {
            unsigned int lo = 0, hi = 0;
#pragma unroll
            for (int r = 0; r < 4; ++r) {
                int mrow = m0 + wm * 32 + mt * 16 + lgrp * 4 + r;
                float val = acc[mt][nt][r] + bs;
                if constexpr (MODE == 0) {
                    vmin = fminf(vmin, val);
                    vmax = fmaxf(vmax, val);
                    int b = mrow >> 11, s = mrow & 2047, h = ncol >> 6, d = ncol & 63;
                    unsigned short bfv = f2bf(val);
                    outb[(size_t)((b * 16 + h) * 2048 + s) * 64 + d] = bfv;
                    if (r < 2) lo |= ((unsigned int)bfv) << (16 * r);
                    else       hi |= ((unsigned int)bfv) << (16 * (r - 2));
                } else {
                    outf[(size_t)mrow * 1024 + ncol] = val;
                }
            }
            if constexpr (MODE == 0) {  // fused transpose write: 4 consecutive s at fixed d
                int mrow0 = m0 + wm * 32 + mt * 16 + lgrp * 4;
                int b = mrow0 >> 11, s0 = mrow0 & 2047;
                int h = ncol >> 6, d = ncol & 63;
                uint2 pk; pk.x = lo; pk.y = hi;
                *(uint2*)&vtb[((size_t)(b * 16 + h) * 64 + d) * 2048 + s0] = pk;
            }
        }
    }
    if constexpr (MODE == 0) {
#pragma unroll
        for (int m = 1; m < 64; m <<= 1) {
            vmin = fminf(vmin, __shfl_xor(vmin, m));
            vmax = fmaxf(vmax, __shfl_xor(vmax, m));
        }
        if (lane == 0) {
            int b = m0 >> 11;
            atomicMin(&mm[b * 2], fenc(vmin));
            atomicMax(&mm[b * 2 + 1], fenc(vmax));
        }
    }
}

// ---- hierarchical prefix scan over s (2048 chains of length 2048) ----
// pass 1: one wave per (bh, 32-row chunk); lane=d sums its 32 values -> ps[bh][c][d]
__global__ __launch_bounds__(256) void k_scan1(const unsigned short* __restrict__ vb,
                                               float* __restrict__ ps) {
    int g = blockIdx.x * 4 + (threadIdx.x >> 6);
    int d = threadIdx.x & 63;
    int bh = g >> 6, c = g & 63;
    const unsigned short* src = vb + (size_t)bh * S_ * 64 + (size_t)c * 32 * 64 + d;
    float a0 = 0.f, a1 = 0.f, a2 = 0.f, a3 = 0.f;
#pragma unroll
    for (int i = 0; i < 32; i += 4) {
        a0 += bf2f(src[(size_t)i * 64]);
        a1 += bf2f(src[(size_t)(i + 1) * 64]);
        a2 += bf2f(src[(size_t)(i + 2) * 64]);
        a3 += bf2f(src[(size_t)(i + 3) * 64]);
    }
    ps[(size_t)g * 64 + d] = (a0 + a1) + (a2 + a3);
}

// pass 2: one thread per (bh,d); register scan of 64 chunk sums -> exclusive base[bh][c][d]
__global__ __launch_bounds__(64) void k_scan2(const float* __restrict__ ps,
                                              float* __restrict__ base) {
    int bh = blockIdx.x;
    int d = threadIdx.x;
    const float* p = ps + (size_t)bh * 64 * 64 + d;
    float* bo = base + (size_t)bh * 64 * 64 + d;
    float vals[64];
#pragma unroll
    for (int c = 0; c < 64; ++c) vals[c] = p[(size_t)c * 64];
    float run = 0.f;
#pragma unroll
    for (int c = 0; c < 64; ++c) {
        float t = vals[c];
        vals[c] = run;
        run += t;
    }
#pragma unroll
    for (int c = 0; c < 64; ++c) bo[(size_t)c * 64] = vals[c];
}

// pass 3: one wave per (bh, chunk); resume scan from base, fuse rowsum -> gene directly.
// gene = inv / rowsum(inv) * ir * log2e  (ir folded; log2e folded so attn uses exp2;
// min-shift cancels in softmax)
__global__ __launch_bounds__(256) void k_scan3(const unsigned short* __restrict__ vb,
                                               const float* __restrict__ base,
                                               unsigned short* __restrict__ gene,
                                               const unsigned int* __restrict__ mm) {
    int g = blockIdx.x * 4 + (threadIdx.x >> 6);
    int d = threadIdx.x & 63;
    int bh = g >> 6, c = g & 63;
    int b = bh >> 4;
    float vmin = fdec(mm[b * 2]), vmax = fdec(mm[b * 2 + 1]);
    float ir = __fdividef(1.0f, vmax - vmin + 1e-8f);
    float irl = ir * 1.4426950408889634f;
    const unsigned short* src = vb + (size_t)bh * S_ * 64 + (size_t)c * 32 * 64 + d;
    unsigned short* dst = gene + (size_t)bh * S_ * 64 + (size_t)c * 32 * 64 + d;
    float acc = base[(size_t)g * 64 + d];
#pragma unroll 4
    for (int i = 0; i < 32; ++i) {
        int s = c * 32 + i;
        acc += bf2f(src[(size_t)i * 64]);
        float phi = __fdividef(acc, (float)(s + 1));
        float inv = __fdividef(1.0f, (phi - vmin) * ir + 0.5f);
        float rs = inv;
#pragma unroll
        for (int m = 1; m < 64; m <<= 1) rs += __shfl_xor(rs, m);
        dst[(size_t)i * 64] = f2bf(__fdividef(inv, rs) * irl);
    }
}

// Fixed-max flash attention v5: uniform small blocks for occupancy + backfill.
// Block = 4 waves x 16 query rows = 64 rows of one bh; key tile = 64. ALL waves share the
// SAME key range (njt = qt+1, uniform in block - no idle waves). Grid = 1024 longest-first
// -> 4 blocks/CU resident (LDS 40 KB) with backfill. Depth-1 DMA prefetch, ONE barrier/tile:
// vmcnt(0) -> barrier -> ASTAGE(jt+1 into buf whose reads finished in jt-1) -> compute(jt).
// QK swapped: mfma(A=v_j, B=gene_i) -> lane holds P[j=4lgrp+r][i=lrow]; cvt_pk -> uint2
// swizzled P^T writes, read b128 as PV's B-operand: out^T = mfma(T_d, P^T).
// p = exp2(s - C2) fixed shift: no running max; denom = per-lane sum + 2 shuffles.
__global__ __launch_bounds__(256, 4) void k_attn(const unsigned short* __restrict__ gene,
                                                 const unsigned short* __restrict__ vb,
                                                 const unsigned short* __restrict__ vt,
                                                 unsigned short* __restrict__ attn_out,
                                                 const unsigned int* __restrict__ mm) {
    __shared__ __align__(16) unsigned short Vsm[2][4096];   // [buf][j 64][d 64] linear
    __shared__ __align__(16) unsigned short Tsm[2][4096];   // [buf][d 64][j 64] linear
    __shared__ __align__(16) unsigned short plds[4][1024];  // per-wave P^T [i 16][j 64] swz
    int tid = threadIdx.x, lane = tid & 63, w = tid >> 6;
    int bid = blockIdx.x;
    int qt = 31 - (bid >> 5);                      // 64-row q tile, longest first
    int bh = ((bid & 7) << 2) | ((bid >> 3) & 3);  // XCD-major bh
    int i0 = qt * 64 + w * 16;
    int lrow = lane & 15, lgrp = lane >> 4;
    int sx = lrow & 7;
    int r8 = lane >> 3, ch = lane & 7;

    int b = bh >> 4;
    float vmin = fdec(mm[b * 2]), vmax = fdec(mm[b * 2 + 1]);
    float ir = __fdividef(1.0f, vmax - vmin + 1e-8f);
    float C2 = (vmin * ir + 1.0f) * 1.4426950408889634f;  // fixed softmax shift, log2 domain

    const unsigned short* gbase = gene + (size_t)bh * S_ * 64;
    const unsigned short* vbase = vb + (size_t)bh * S_ * 64;
    const unsigned short* tbase = vt + (size_t)bh * 64 * S_;

    // DMA staging sources (pre-swizzled chunk)
    const unsigned short* Vg = vbase + (size_t)(w * 8 + r8) * 64 + ((ch ^ r8) << 3);
    const unsigned short* Tg = tbase + (size_t)(w * 8 + r8) * S_ + ((ch ^ r8) << 3);

#define ASTAGE(buf, jt_)                                                                  \
    {                                                                                     \
        int j0s = (jt_) << 6;                                                             \
        _Pragma("unroll") for (int i = 0; i < 2; ++i)                                     \
            gload16(Vg + (size_t)(j0s + i * 32) * 64, &Vsm[buf][(i * 32 + w * 8) * 64]);  \
        _Pragma("unroll") for (int i = 0; i < 2; ++i)                                     \
            gload16(Tg + (size_t)(i * 32) * S_ + j0s, &Tsm[buf][(i * 32 + w * 8) * 64]);  \
    }

    bf16x8 ga0 = *(const bf16x8*)(gbase + (size_t)(i0 + lrow) * 64 + lgrp * 8);
    bf16x8 ga1 = *(const bf16x8*)(gbase + (size_t)(i0 + lrow) * 64 + 32 + lgrp * 8);

    f32x4 acc[4];
#pragma unroll
    for (int dn = 0; dn < 4; ++dn) acc[dn] = (f32x4){0.f, 0.f, 0.f, 0.f};
    float lsum = 0.f;

    int njt = qt + 1;  // uniform across the block's 4 waves
    ASTAGE(0, 0);
    for (int jt = 0; jt < njt; ++jt) {
        int cur = jt & 1;
        asm volatile("s_waitcnt vmcnt(0)" ::: "memory");  // tile jt landed (issued 1 compute ago)
        __builtin_amdgcn_s_barrier();   // all waves consumed buf[(jt-1)&1] reads in iter jt-1
        __builtin_amdgcn_sched_barrier(0);
        if (jt + 1 < njt) ASTAGE(cur ^ 1, jt + 1);  // safe: that buf's reads done
        int j0 = jt << 6;
        __builtin_amdgcn_s_setprio(1);
        // ---- swapped scores: D[j=4lgrp+r][i=lrow] ----
        f32x4 Sv[4];
#pragma unroll
        for (int n = 0; n < 4; ++n) {
            const unsigned short* vr = &Vsm[cur][(n * 16 + lrow) * 64];
            bf16x8 a0 = *(const bf16x8*)(vr + ((lgrp ^ sx) << 3));
            bf16x8 a1 = *(const bf16x8*)(vr + (((lgrp + 4) ^ sx) << 3));
            f32x4 c = (f32x4){0.f, 0.f, 0.f, 0.f};
            c = mfma16(a0, ga0, c);
            c = mfma16(a1, ga1, c);
            Sv[n] = c;
        }
        bool tail = (jt == njt - 1);
        // ---- p = exp2(s - C2); per-lane denom; pack; swizzled 8B P^T writes ----
#pragma unroll
        for (int n = 0; n < 4; ++n) {
            float q0 = exp2f(Sv[n][0] - C2);
            float q1 = exp2f(Sv[n][1] - C2);
            float q2 = exp2f(Sv[n][2] - C2);
            float q3 = exp2f(Sv[n][3] - C2);
            if (tail) {
                int ii = i0 + lrow;
                int jj = j0 + n * 16 + 4 * lgrp;
                q0 = (jj     <= ii) ? q0 : 0.f;
                q1 = (jj + 1 <= ii) ? q1 : 0.f;
                q2 = (jj + 2 <= ii) ? q2 : 0.f;
                q3 = (jj + 3 <= ii) ? q3 : 0.f;
            }
            lsum += (q0 + q1) + (q2 + q3);
            uint2 pk;
            pk.x = cvt_pk_bf16(q0, q1);
            pk.y = cvt_pk_bf16(q2, q3);
            int chunk = 2 * n + (lgrp >> 1);
            *(uint2*)&plds[w][lrow * 64 + ((chunk ^ sx) << 3) + ((lgrp & 1) << 2)] = pk;
        }
        // wave-local LDS RAW: DS ops in-order per wave; compiler inserts lgkmcnt.
        // ---- PV^T: acc[dn] += T(16d x 32j) * P^T(16i x 32j) ----
#pragma unroll
        for (int chk = 0; chk < 2; ++chk) {
            int pc = ((chk * 4 + lgrp) ^ sx) << 3;
            bf16x8 pa = *(const bf16x8*)&plds[w][lrow * 64 + pc];
#pragma unroll
            for (int dn = 0; dn < 4; ++dn) {
                bf16x8 tf = *(const bf16x8*)&Tsm[cur][(dn * 16 + lrow) * 64 + pc];
                acc[dn] = mfma16(tf, pa, acc[dn]);
            }
        }
        __builtin_amdgcn_s_setprio(0);
    }
#undef ASTAGE
    // denominator: sum across the 4 lgrp groups (j-partials)
    lsum += __shfl_xor(lsum, 16);
    lsum += __shfl_xor(lsum, 32);
    lsum = __fdividef(1.0f, lsum);
    int bb = bh >> 4, h = bh & 15;
    int ii = i0 + lrow;
#pragma unroll
    for (int dn = 0; dn < 4; ++dn) {
        uint2 pk;
        pk.x = cvt_pk_bf16(acc[dn][0] * lsum, acc[dn][1] * lsum);
        pk.y = cvt_pk_bf16(acc[dn][2] * lsum, acc[dn][3] * lsum);
        int e = h * 64 + dn * 16 + lgrp * 4;
        *(uint2*)&attn_out[(size_t)(bb * S_ + ii) * E_ + e] = pk;
    }
}

extern "C" void kernel_launch(void* const* d_in, const int* in_sizes, int n_in,
                              void* d_out, int out_size, void* d_ws, size_t ws_size,
                              hipStream_t stream) {
    const float* x = (const float*)d_in[0];
    const float* wv_w = (const float*)d_in[1];
    const float* wv_b = (const float*)d_in[2];
    const float* wo_w = (const float*)d_in[3];
    const float* wo_b = (const float*)d_in[4];
    float* out = (float*)d_out;

    char* w = (char*)d_ws;
    unsigned short* x_bf = (unsigned short*)(w);               // 8 MB
    unsigned short* wv_bf = (unsigned short*)(w + 8388608);    // 2 MB
    unsigned short* wo_bf = (unsigned short*)(w + 10485760);   // 2 MB
    unsigned short* v_bf = (unsigned short*)(w + 12582912);    // 8 MB  [b][h][s][d]
    unsigned short* vt_bf = (unsigned short*)(w + 20971520);   // 8 MB  [b][h][d][s]
    float* ps = (float*)(w + 29360128);                        // 512 KB [bh][c][d]
    float* base = (float*)(w + 29884416);                      // 512 KB [bh][c][d]
    unsigned short* gene = (unsigned short*)(w + 46137344);    // 8 MB
    unsigned short* a_bf = (unsigned short*)(w + 54525952);    // 8 MB  [b][s][e]
    unsigned int* mm = (unsigned int*)(w + 62914560);          // 16 B
    if (ws_size < 62914576) return;  // insufficient workspace -> fail loudly

    k_init<<<1, 64, 0, stream>>>(mm);
    k_cast<<<2048, 256, 0, stream>>>(x, x_bf, 524288);
    k_cast<<<512, 256, 0, stream>>>(wv_w, wv_bf, 131072);
    k_cast<<<512, 256, 0, stream>>>(wo_w, wo_bf, 131072);
    k_gemm<0><<<dim3(64, 16), 256, 0, stream>>>(x_bf, wv_bf, wv_b, v_bf, vt_bf, nullptr, mm);
    k_scan1<<<512, 256, 0, stream>>>(v_bf, ps);
    k_scan2<<<32, 64, 0, stream>>>(ps, base);
    k_scan3<<<512, 256, 0, stream>>>(v_bf, base, gene, mm);
    k_attn<<<1024, 256, 0, stream>>>(gene, v_bf, vt_bf, a_bf, mm);
    k_gemm<1><<<dim3(64, 16), 256, 0, stream>>>(a_bf, wo_bf, wo_b, nullptr, nullptr, out, nullptr);
}

// Round 18
// 138.313 us; speedup vs baseline: 1.4565x; 1.4565x over previous
//
#include <hip/hip_runtime.h>
#include <hip/hip_bf16.h>

#define B_ 2
#define S_ 2048
#define E_ 1024
#define H_ 16
#define D_ 64
#define M_ 4096  // B_*S_

typedef __bf16 bf16_t;
typedef bf16_t bf16x8 __attribute__((ext_vector_type(8)));
typedef float f32x4 __attribute__((ext_vector_type(4)));
typedef unsigned int u32;

__device__ __forceinline__ f32x4 mfma16(bf16x8 a, bf16x8 b, f32x4 c) {
    return __builtin_amdgcn_mfma_f32_16x16x32_bf16(a, b, c, 0, 0, 0);
}
__device__ __forceinline__ unsigned short f2bf(float f) {
    unsigned int u = __float_as_uint(f);
    unsigned int r = (u + 0x7fffu + ((u >> 16) & 1u)) >> 16;
    return (unsigned short)r;
}
__device__ __forceinline__ float bf2f(unsigned short s) {
    return __uint_as_float(((unsigned int)s) << 16);
}
// pack two f32 -> dword of 2 bf16 (src0 -> low half), RTNE
__device__ __forceinline__ u32 cvt_pk_bf16(float lo, float hi) {
    u32 r;
    asm("v_cvt_pk_bf16_f32 %0, %1, %2" : "=v"(r) : "v"(lo), "v"(hi));
    return r;
}
// order-preserving float<->uint for atomic min/max
__device__ __forceinline__ unsigned int fenc(float x) {
    unsigned int u = __float_as_uint(x);
    return (u & 0x80000000u) ? ~u : (u | 0x80000000u);
}
__device__ __forceinline__ float fdec(unsigned int u) {
    return __uint_as_float((u & 0x80000000u) ? (u ^ 0x80000000u) : ~u);
}
// async global->LDS DMA, 16B per lane; LDS dest = wave-uniform base + lane*16
__device__ __forceinline__ void gload16(const void* g, void* l) {
    __builtin_amdgcn_global_load_lds((const __attribute__((address_space(1))) u32*)g,
                                     (__attribute__((address_space(3))) u32*)l, 16, 0, 0);
}

__global__ void k_init(unsigned int* mm) {
    int t = threadIdx.x;
    if (t < 2) { mm[t * 2] = 0xFFFFFFFFu; mm[t * 2 + 1] = 0u; }
}

// cast f32 rows x 1024 -> bf16 K-BLOCKED layout [16][rows][64] (kt = k/64).
// Each K-step tile is then a contiguous run -> gemm staging loads are 1KB-contiguous
// per wave instruction (the attn-proven fast VMEM pattern; breaks the 2KB-stride
// L2 channel serialization that capped gemm at ~2.5 TB/s).
__global__ __launch_bounds__(256) void k_castp(const float* __restrict__ src,
                                               unsigned short* __restrict__ dst,
                                               int n8, int rows) {
    int i = blockIdx.x * 256 + threadIdx.x;
    if (i >= n8) return;
    int m = (i * 8) >> 10, k = (i * 8) & 1023;
    int kt = k >> 6, ko = k & 63;
    const float4* s4 = (const float4*)src;
    float4 a = s4[2 * i], c = s4[2 * i + 1];
    uint4 o;
    o.x = cvt_pk_bf16(a.x, a.y);
    o.y = cvt_pk_bf16(a.z, a.w);
    o.z = cvt_pk_bf16(c.x, c.y);
    o.w = cvt_pk_bf16(c.z, c.w);
    *(uint4*)&dst[((size_t)kt * rows + m) * 64 + ko] = o;
}

// C[m][n] = sum_k A[m][k]*B[n][k] + bias[n].  A blocked [16][4096][64], B blocked [16][1024][64].
// r13 structure (best measured): 128x128 tile, 4 waves (64x64 each), BK=64,
// global_load_lds(16B) double-buffered, counted vmcnt(8), 2 barriers/step.
// NEW: blocked operand layouts make every staging instruction read 1KB CONTIGUOUS
// (8 rows x 128B adjacent) instead of 2KB-strided - the attn-measured fast path.
// Swizzle: pre-swizzled GLOBAL source (chunk ^= row&7), same XOR on ds_read; LDS linear.
// MODE 0: write bf16 v [b][h][s][d] + transposed vt [b][h][d][s] + per-batch min/max atomics.
// MODE 1: write fp32 outf[m][n].
template <int MODE>
__global__ __launch_bounds__(256, 2) void k_gemm(const unsigned short* __restrict__ A,
                                                 const unsigned short* __restrict__ Bm,
                                                 const float* __restrict__ bias,
                                                 unsigned short* __restrict__ outb,
                                                 unsigned short* __restrict__ vtb,
                                                 float* __restrict__ outf,
                                                 unsigned int* __restrict__ mm) {
    __shared__ __align__(16) unsigned short Asm[2][8192];  // [buf][128 rows x 64 shorts]
    __shared__ __align__(16) unsigned short Bsm[2][8192];  // [buf][128 rows x 64 shorts]
    const size_t AKT = (size_t)M_ * 64;    // 262144 shorts per A k-block
    const size_t BKT = (size_t)1024 * 64;  // 65536 shorts per B k-block
    int tid = threadIdx.x, lane = tid & 63, wv = tid >> 6;
    int wm = wv >> 1, wn = wv & 1;
    int m0 = blockIdx.x * 128, n0 = blockIdx.y * 128;
    int lrow = lane & 15, lgrp = lane >> 4, sw = lane & 7;
    int r8 = lane >> 3, ch = lane & 7;
    // pre-swizzled blocked sources: lane covers (row = i*32 + wv*8 + r8, 16B chunk = ch ^ r8)
    const unsigned short* Ag = A + (size_t)(m0 + wv * 8 + r8) * 64 + ((ch ^ r8) << 3);
    const unsigned short* Bg = Bm + (size_t)(n0 + wv * 8 + r8) * 64 + ((ch ^ r8) << 3);

#define STAGE(buf, tt)                                                                        \
    {                                                                                         \
        _Pragma("unroll") for (int i = 0; i < 4; ++i)                                         \
            gload16(Ag + (size_t)(tt)*AKT + (size_t)(i * 32) * 64,                            \
                    &Asm[buf][(i * 32 + wv * 8) * 64]);                                       \
        _Pragma("unroll") for (int i = 0; i < 4; ++i)                                         \
            gload16(Bg + (size_t)(tt)*BKT + (size_t)(i * 32) * 64,                            \
                    &Bsm[buf][(i * 32 + wv * 8) * 64]);                                       \
    }
#define COMPUTE(buf)                                                                        \
    {                                                                                       \
        _Pragma("unroll") for (int kh = 0; kh < 2; ++kh) {                                  \
            int cp = (((kh << 2) | lgrp) ^ sw) << 3;                                        \
            bf16x8 af[4], bfr[4];                                                           \
            _Pragma("unroll") for (int mt = 0; mt < 4; ++mt)                                \
                af[mt] = *(const bf16x8*)&Asm[buf][(wm * 64 + mt * 16 + lrow) * 64 + cp];   \
            _Pragma("unroll") for (int nt = 0; nt < 4; ++nt)                                \
                bfr[nt] = *(const bf16x8*)&Bsm[buf][(wn * 64 + nt * 16 + lrow) * 64 + cp];  \
            _Pragma("unroll") for (int mt = 0; mt < 4; ++mt)                                \
                _Pragma("unroll") for (int nt = 0; nt < 4; ++nt)                            \
                    acc[mt][nt] = mfma16(af[mt], bfr[nt], acc[mt][nt]);                     \
        }                                                                                   \
    }

    f32x4 acc[4][4];
#pragma unroll
    for (int i = 0; i < 4; ++i)
#pragma unroll
        for (int j = 0; j < 4; ++j) acc[i][j] = (f32x4){0.f, 0.f, 0.f, 0.f};

    STAGE(0, 0);
    STAGE(1, 1);
    for (int t = 0; t < 15; ++t) {
        asm volatile("s_waitcnt vmcnt(8)" ::: "memory");  // buf[t&1] landed; t+1's 8 stay in flight
        __builtin_amdgcn_s_barrier();
        __builtin_amdgcn_sched_barrier(0);
        COMPUTE(t & 1);
        asm volatile("s_waitcnt lgkmcnt(0)" ::: "memory");  // my reads done before overwrite
        __builtin_amdgcn_s_barrier();
        __builtin_amdgcn_sched_barrier(0);
        if (t < 14) STAGE(t & 1, t + 2);
    }
    asm volatile("s_waitcnt vmcnt(0)" ::: "memory");
    __builtin_amdgcn_s_barrier();
    __builtin_amdgcn_sched_barrier(0);
    COMPUTE(1);
#undef STAGE
#undef COMPUTE

    float vmin = 1e30f, vmax = -1e30f;
#pragma unroll
    for (int nt = 0; nt < 4; ++nt) {
        int ncol = n0 + wn * 64 + nt * 16 + lrow;
        float bs = bias[ncol];
#pragma unroll
        for (int mt = 0; mt < 4; ++mt) {
            unsigned int lo = 0, hi = 0;
#pragma unroll
            for (int r = 0; r < 4; ++r) {
                int mrow = m0 + wm * 64 + mt * 16 + lgrp * 4 + r;
                float val = acc[mt][nt][r] + bs;
                if constexpr (MODE == 0) {
                    vmin = fminf(vmin, val);
                    vmax = fmaxf(vmax, val);
                    int b = mrow >> 11, s = mrow & 2047, h = ncol >> 6, d = ncol & 63;
                    unsigned short bfv = f2bf(val);
                    outb[(size_t)((b * 16 + h) * 2048 + s) * 64 + d] = bfv;
                    if (r < 2) lo |= ((unsigned int)bfv) << (16 * r);
                    else       hi |= ((unsigned int)bfv) << (16 * (r - 2));
                } else {
                    outf[(size_t)mrow * 1024 + ncol] = val;
                }
            }
            if constexpr (MODE == 0) {  // fused transpose write: 4 consecutive s at fixed d
                int mrow0 = m0 + wm * 64 + mt * 16 + lgrp * 4;
                int b = mrow0 >> 11, s0 = mrow0 & 2047;
                int h = ncol >> 6, d = ncol & 63;
                uint2 pk; pk.x = lo; pk.y = hi;
                *(uint2*)&vtb[((size_t)(b * 16 + h) * 64 + d) * 2048 + s0] = pk;
            }
        }
    }
    if constexpr (MODE == 0) {
#pragma unroll
        for (int m = 1; m < 64; m <<= 1) {
            vmin = fminf(vmin, __shfl_xor(vmin, m));
            vmax = fmaxf(vmax, __shfl_xor(vmax, m));
        }
        if (lane == 0) {
            int b = m0 >> 11;
            atomicMin(&mm[b * 2], fenc(vmin));
            atomicMax(&mm[b * 2 + 1], fenc(vmax));
        }
    }
}

// ---- hierarchical prefix scan over s (2048 chains of length 2048) ----
// pass 1: one wave per (bh, 32-row chunk); lane=d sums its 32 values -> ps[bh][c][d]
__global__ __launch_bounds__(256) void k_scan1(const unsigned short* __restrict__ vb,
                                               float* __restrict__ ps) {
    int g = blockIdx.x * 4 + (threadIdx.x >> 6);
    int d = threadIdx.x & 63;
    int bh = g >> 6, c = g & 63;
    const unsigned short* src = vb + (size_t)bh * S_ * 64 + (size_t)c * 32 * 64 + d;
    float a0 = 0.f, a1 = 0.f, a2 = 0.f, a3 = 0.f;
#pragma unroll
    for (int i = 0; i < 32; i += 4) {
        a0 += bf2f(src[(size_t)i * 64]);
        a1 += bf2f(src[(size_t)(i + 1) * 64]);
        a2 += bf2f(src[(size_t)(i + 2) * 64]);
        a3 += bf2f(src[(size_t)(i + 3) * 64]);
    }
    ps[(size_t)g * 64 + d] = (a0 + a1) + (a2 + a3);
}

// pass 2: one thread per (bh,d); register scan of 64 chunk sums -> exclusive base[bh][c][d]
__global__ __launch_bounds__(64) void k_scan2(const float* __restrict__ ps,
                                              float* __restrict__ base) {
    int bh = blockIdx.x;
    int d = threadIdx.x;
    const float* p = ps + (size_t)bh * 64 * 64 + d;
    float* bo = base + (size_t)bh * 64 * 64 + d;
    float vals[64];
#pragma unroll
    for (int c = 0; c < 64; ++c) vals[c] = p[(size_t)c * 64];
    float run = 0.f;
#pragma unroll
    for (int c = 0; c < 64; ++c) {
        float t = vals[c];
        vals[c] = run;
        run += t;
    }
#pragma unroll
    for (int c = 0; c < 64; ++c) bo[(size_t)c * 64] = vals[c];
}

// pass 3: one wave per (bh, chunk); resume scan from base, fuse rowsum -> gene directly.
// gene = inv / rowsum(inv) * ir * log2e  (ir folded; log2e folded so attn uses exp2;
// min-shift cancels in softmax)
__global__ __launch_bounds__(256) void k_scan3(const unsigned short* __restrict__ vb,
                                               const float* __restrict__ base,
                                               unsigned short* __restrict__ gene,
                                               const unsigned int* __restrict__ mm) {
    int g = blockIdx.x * 4 + (threadIdx.x >> 6);
    int d = threadIdx.x & 63;
    int bh = g >> 6, c = g & 63;
    int b = bh >> 4;
    float vmin = fdec(mm[b * 2]), vmax = fdec(mm[b * 2 + 1]);
    float ir = __fdividef(1.0f, vmax - vmin + 1e-8f);
    float irl = ir * 1.4426950408889634f;
    const unsigned short* src = vb + (size_t)bh * S_ * 64 + (size_t)c * 32 * 64 + d;
    unsigned short* dst = gene + (size_t)bh * S_ * 64 + (size_t)c * 32 * 64 + d;
    float acc = base[(size_t)g * 64 + d];
#pragma unroll 4
    for (int i = 0; i < 32; ++i) {
        int s = c * 32 + i;
        acc += bf2f(src[(size_t)i * 64]);
        float phi = __fdividef(acc, (float)(s + 1));
        float inv = __fdividef(1.0f, (phi - vmin) * ir + 0.5f);
        float rs = inv;
#pragma unroll
        for (int m = 1; m < 64; m <<= 1) rs += __shfl_xor(rs, m);
        dst[(size_t)i * 64] = f2bf(__fdividef(inv, rs) * irl);
    }
}

// Fixed-max flash attention v5: uniform small blocks for occupancy + backfill.
// Block = 4 waves x 16 query rows = 64 rows of one bh; key tile = 64. ALL waves share the
// SAME key range (njt = qt+1, uniform in block - no idle waves). Grid = 1024 longest-first
// -> 4 blocks/CU resident (LDS 40 KB) with backfill. Depth-1 DMA prefetch, ONE barrier/tile.
// QK swapped: mfma(A=v_j, B=gene_i) -> lane holds P[j=4lgrp+r][i=lrow]; cvt_pk -> uint2
// swizzled P^T writes, read b128 as PV's B-operand: out^T = mfma(T_d, P^T).
// p = exp2(s - C2) fixed shift: no running max; denom = per-lane sum + 2 shuffles.
// OUTPUT: K-blocked a_p[h][m][64] (kt == h since E-block 64 == head dim) for the wo gemm.
__global__ __launch_bounds__(256, 4) void k_attn(const unsigned short* __restrict__ gene,
                                                 const unsigned short* __restrict__ vb,
                                                 const unsigned short* __restrict__ vt,
                                                 unsigned short* __restrict__ attn_out,
                                                 const unsigned int* __restrict__ mm) {
    __shared__ __align__(16) unsigned short Vsm[2][4096];   // [buf][j 64][d 64] linear
    __shared__ __align__(16) unsigned short Tsm[2][4096];   // [buf][d 64][j 64] linear
    __shared__ __align__(16) unsigned short plds[4][1024];  // per-wave P^T [i 16][j 64] swz
    int tid = threadIdx.x, lane = tid & 63, w = tid >> 6;
    int bid = blockIdx.x;
    int qt = 31 - (bid >> 5);                      // 64-row q tile, longest first
    int bh = ((bid & 7) << 2) | ((bid >> 3) & 3);  // XCD-major bh
    int i0 = qt * 64 + w * 16;
    int lrow = lane & 15, lgrp = lane >> 4;
    int sx = lrow & 7;
    int r8 = lane >> 3, ch = lane & 7;

    int b = bh >> 4;
    float vmin = fdec(mm[b * 2]), vmax = fdec(mm[b * 2 + 1]);
    float ir = __fdividef(1.0f, vmax - vmin + 1e-8f);
    float C2 = (vmin * ir + 1.0f) * 1.4426950408889634f;  // fixed softmax shift, log2 domain

    const unsigned short* gbase = gene + (size_t)bh * S_ * 64;
    const unsigned short* vbase = vb + (size_t)bh * S_ * 64;
    const unsigned short* tbase = vt + (size_t)bh * 64 * S_;

    // DMA staging sources (pre-swizzled chunk)
    const unsigned short* Vg = vbase + (size_t)(w * 8 + r8) * 64 + ((ch ^ r8) << 3);
    const unsigned short* Tg = tbase + (size_t)(w * 8 + r8) * S_ + ((ch ^ r8) << 3);

#define ASTAGE(buf, jt_)                                                                  \
    {                                                                                     \
        int j0s = (jt_) << 6;                                                             \
        _Pragma("unroll") for (int i = 0; i < 2; ++i)                                     \
            gload16(Vg + (size_t)(j0s + i * 32) * 64, &Vsm[buf][(i * 32 + w * 8) * 64]);  \
        _Pragma("unroll") for (int i = 0; i < 2; ++i)                                     \
            gload16(Tg + (size_t)(i * 32) * S_ + j0s, &Tsm[buf][(i * 32 + w * 8) * 64]);  \
    }

    bf16x8 ga0 = *(const bf16x8*)(gbase + (size_t)(i0 + lrow) * 64 + lgrp * 8);
    bf16x8 ga1 = *(const bf16x8*)(gbase + (size_t)(i0 + lrow) * 64 + 32 + lgrp * 8);

    f32x4 acc[4];
#pragma unroll
    for (int dn = 0; dn < 4; ++dn) acc[dn] = (f32x4){0.f, 0.f, 0.f, 0.f};
    float lsum = 0.f;

    int njt = qt + 1;  // uniform across the block's 4 waves
    ASTAGE(0, 0);
    for (int jt = 0; jt < njt; ++jt) {
        int cur = jt & 1;
        asm volatile("s_waitcnt vmcnt(0)" ::: "memory");  // tile jt landed (issued 1 compute ago)
        __builtin_amdgcn_s_barrier();   // all waves consumed buf[(jt-1)&1] reads in iter jt-1
        __builtin_amdgcn_sched_barrier(0);
        if (jt + 1 < njt) ASTAGE(cur ^ 1, jt + 1);  // safe: that buf's reads done
        int j0 = jt << 6;
        __builtin_amdgcn_s_setprio(1);
        // ---- swapped scores: D[j=4lgrp+r][i=lrow] ----
        f32x4 Sv[4];
#pragma unroll
        for (int n = 0; n < 4; ++n) {
            const unsigned short* vr = &Vsm[cur][(n * 16 + lrow) * 64];
            bf16x8 a0 = *(const bf16x8*)(vr + ((lgrp ^ sx) << 3));
            bf16x8 a1 = *(const bf16x8*)(vr + (((lgrp + 4) ^ sx) << 3));
            f32x4 c = (f32x4){0.f, 0.f, 0.f, 0.f};
            c = mfma16(a0, ga0, c);
            c = mfma16(a1, ga1, c);
            Sv[n] = c;
        }
        bool tail = (jt == njt - 1);
        // ---- p = exp2(s - C2); per-lane denom; pack; swizzled 8B P^T writes ----
#pragma unroll
        for (int n = 0; n < 4; ++n) {
            float q0 = exp2f(Sv[n][0] - C2);
            float q1 = exp2f(Sv[n][1] - C2);
            float q2 = exp2f(Sv[n][2] - C2);
            float q3 = exp2f(Sv[n][3] - C2);
            if (tail) {
                int ii = i0 + lrow;
                int jj = j0 + n * 16 + 4 * lgrp;
                q0 = (jj     <= ii) ? q0 : 0.f;
                q1 = (jj + 1 <= ii) ? q1 : 0.f;
                q2 = (jj + 2 <= ii) ? q2 : 0.f;
                q3 = (jj + 3 <= ii) ? q3 : 0.f;
            }
            lsum += (q0 + q1) + (q2 + q3);
            uint2 pk;
            pk.x = cvt_pk_bf16(q0, q1);
            pk.y = cvt_pk_bf16(q2, q3);
            int chunk = 2 * n + (lgrp >> 1);
            *(uint2*)&plds[w][lrow * 64 + ((chunk ^ sx) << 3) + ((lgrp & 1) << 2)] = pk;
        }
        // wave-local LDS RAW: DS ops in-order per wave; compiler inserts lgkmcnt.
        // ---- PV^T: acc[dn] += T(16d x 32j) * P^T(16i x 32j) ----
#pragma unroll
        for (int chk = 0; chk < 2; ++chk) {
            int pc = ((chk * 4 + lgrp) ^ sx) << 3;
            bf16x8 pa = *(const bf16x8*)&plds[w][lrow * 64 + pc];
#pragma unroll
            for (int dn = 0; dn < 4; ++dn) {
                bf16x8 tf = *(const bf16x8*)&Tsm[cur][(dn * 16 + lrow) * 64 + pc];
                acc[dn] = mfma16(tf, pa, acc[dn]);
            }
        }
        __builtin_amdgcn_s_setprio(0);
    }
#undef ASTAGE
    // denominator: sum across the 4 lgrp groups (j-partials)
    lsum += __shfl_xor(lsum, 16);
    lsum += __shfl_xor(lsum, 32);
    lsum = __fdividef(1.0f, lsum);
    int bb = bh >> 4, h = bh & 15;
    int ii = i0 + lrow;
#pragma unroll
    for (int dn = 0; dn < 4; ++dn) {
        uint2 pk;
        pk.x = cvt_pk_bf16(acc[dn][0] * lsum, acc[dn][1] * lsum);
        pk.y = cvt_pk_bf16(acc[dn][2] * lsum, acc[dn][3] * lsum);
        // K-blocked output: a_p[kt=h][m=bb*S_+ii][64] at offset dn*16 + lgrp*4
        *(uint2*)&attn_out[((size_t)h * M_ + bb * S_ + ii) * 64 + dn * 16 + lgrp * 4] = pk;
    }
}

extern "C" void kernel_launch(void* const* d_in, const int* in_sizes, int n_in,
                              void* d_out, int out_size, void* d_ws, size_t ws_size,
                              hipStream_t stream) {
    const float* x = (const float*)d_in[0];
    const float* wv_w = (const float*)d_in[1];
    const float* wv_b = (const float*)d_in[2];
    const float* wo_w = (const float*)d_in[3];
    const float* wo_b = (const float*)d_in[4];
    float* out = (float*)d_out;

    char* w = (char*)d_ws;
    unsigned short* x_bf = (unsigned short*)(w);               // 8 MB  blocked [16][4096][64]
    unsigned short* wv_bf = (unsigned short*)(w + 8388608);    // 2 MB  blocked [16][1024][64]
    unsigned short* wo_bf = (unsigned short*)(w + 10485760);   // 2 MB  blocked [16][1024][64]
    unsigned short* v_bf = (unsigned short*)(w + 12582912);    // 8 MB  [b][h][s][d]
    unsigned short* vt_bf = (unsigned short*)(w + 20971520);   // 8 MB  [b][h][d][s]
    float* ps = (float*)(w + 29360128);                        // 512 KB [bh][c][d]
    float* base = (float*)(w + 29884416);                      // 512 KB [bh][c][d]
    unsigned short* gene = (unsigned short*)(w + 46137344);    // 8 MB
    unsigned short* a_bf = (unsigned short*)(w + 54525952);    // 8 MB  blocked [16][4096][64]
    unsigned int* mm = (unsigned int*)(w + 62914560);          // 16 B
    if (ws_size < 62914576) return;  // insufficient workspace -> fail loudly

    k_init<<<1, 64, 0, stream>>>(mm);
    k_castp<<<2048, 256, 0, stream>>>(x, x_bf, 524288, 4096);
    k_castp<<<512, 256, 0, stream>>>(wv_w, wv_bf, 131072, 1024);
    k_castp<<<512, 256, 0, stream>>>(wo_w, wo_bf, 131072, 1024);
    k_gemm<0><<<dim3(32, 8), 256, 0, stream>>>(x_bf, wv_bf, wv_b, v_bf, vt_bf, nullptr, mm);
    k_scan1<<<512, 256, 0, stream>>>(v_bf, ps);
    k_scan2<<<32, 64, 0, stream>>>(ps, base);
    k_scan3<<<512, 256, 0, stream>>>(v_bf, base, gene, mm);
    k_attn<<<1024, 256, 0, stream>>>(gene, v_bf, vt_bf, a_bf, mm);
    k_gemm<1><<<dim3(32, 8), 256, 0, stream>>>(a_bf, wo_bf, wo_b, nullptr, nullptr, out, nullptr);
}

// Round 19
// 130.398 us; speedup vs baseline: 1.5450x; 1.0607x over previous
//
#include <hip/hip_runtime.h>
#include <hip/hip_bf16.h>

#define B_ 2
#define S_ 2048
#define E_ 1024
#define H_ 16
#define D_ 64
#define M_ 4096  // B_*S_

typedef __bf16 bf16_t;
typedef bf16_t bf16x8 __attribute__((ext_vector_type(8)));
typedef float f32x4 __attribute__((ext_vector_type(4)));
typedef unsigned int u32;

__device__ __forceinline__ f32x4 mfma16(bf16x8 a, bf16x8 b, f32x4 c) {
    return __builtin_amdgcn_mfma_f32_16x16x32_bf16(a, b, c, 0, 0, 0);
}
__device__ __forceinline__ unsigned short f2bf(float f) {
    unsigned int u = __float_as_uint(f);
    unsigned int r = (u + 0x7fffu + ((u >> 16) & 1u)) >> 16;
    return (unsigned short)r;
}
__device__ __forceinline__ float bf2f(unsigned short s) {
    return __uint_as_float(((unsigned int)s) << 16);
}
// pack two f32 -> dword of 2 bf16 (src0 -> low half), RTNE
__device__ __forceinline__ u32 cvt_pk_bf16(float lo, float hi) {
    u32 r;
    asm("v_cvt_pk_bf16_f32 %0, %1, %2" : "=v"(r) : "v"(lo), "v"(hi));
    return r;
}
// order-preserving float<->uint for atomic min/max
__device__ __forceinline__ unsigned int fenc(float x) {
    unsigned int u = __float_as_uint(x);
    return (u & 0x80000000u) ? ~u : (u | 0x80000000u);
}
__device__ __forceinline__ float fdec(unsigned int u) {
    return __uint_as_float((u & 0x80000000u) ? (u ^ 0x80000000u) : ~u);
}
// async global->LDS DMA, 16B per lane; LDS dest = wave-uniform base + lane*16
__device__ __forceinline__ void gload16(const void* g, void* l) {
    __builtin_amdgcn_global_load_lds((const __attribute__((address_space(1))) u32*)g,
                                     (__attribute__((address_space(3))) u32*)l, 16, 0, 0);
}

// fused prep: cast x/wv/wo (f32 -> bf16, K-BLOCKED [16][rows][64]) + init min/max atomics.
// blocks 0..2047: x (4096 rows); 2048..2559: wv; 2560..3071: wo.
__global__ __launch_bounds__(256) void k_prep(const float* __restrict__ x,
                                              const float* __restrict__ wv,
                                              const float* __restrict__ wo,
                                              unsigned short* __restrict__ xd,
                                              unsigned short* __restrict__ wvd,
                                              unsigned short* __restrict__ wod,
                                              unsigned int* __restrict__ mm) {
    int bid = blockIdx.x, tid = threadIdx.x;
    if (bid == 0 && tid < 2) { mm[tid * 2] = 0xFFFFFFFFu; mm[tid * 2 + 1] = 0u; }
    const float* src;
    unsigned short* dst;
    int i, rows;
    if (bid < 2048) { src = x;  dst = xd;  i = bid * 256 + tid;          rows = 4096; }
    else if (bid < 2560) { src = wv; dst = wvd; i = (bid - 2048) * 256 + tid; rows = 1024; }
    else { src = wo; dst = wod; i = (bid - 2560) * 256 + tid; rows = 1024; }
    int m = (i * 8) >> 10, k = (i * 8) & 1023;
    int kt = k >> 6, ko = k & 63;
    const float4* s4 = (const float4*)src;
    float4 a = s4[2 * i], c = s4[2 * i + 1];
    uint4 o;
    o.x = cvt_pk_bf16(a.x, a.y);
    o.y = cvt_pk_bf16(a.z, a.w);
    o.z = cvt_pk_bf16(c.x, c.y);
    o.w = cvt_pk_bf16(c.z, c.w);
    *(uint4*)&dst[((size_t)kt * rows + m) * 64 + ko] = o;
}

// C[m][n] = sum_k A[m][k]*B[n][k] + bias[n].  A blocked [16][4096][64], B blocked [16][1024][64].
// r13/r18 structure (best measured): 128x128 tile, 4 waves (64x64 each), BK=64,
// global_load_lds(16B) double-buffered, counted vmcnt(8), 2 barriers/step; blocked layouts
// give 1KB-contiguous staging reads. Swizzle: pre-swizzled GLOBAL source (chunk ^= row&7),
// same XOR on ds_read; LDS writes linear.
// MODE 0: write bf16 v [b][h][s][d] + transposed vt [b][h][d][s] + per-batch min/max atomics
//         + FUSED scan pass 1: 32-row chunk sums of v (incl. bias) -> ps[bh][c][d]
//         (thread holds 8 rows/chunk; 2 shfl_xor over lgrp completes 32; lane<16 stores).
// MODE 1: write fp32 outf[m][n].
template <int MODE>
__global__ __launch_bounds__(256, 2) void k_gemm(const unsigned short* __restrict__ A,
                                                 const unsigned short* __restrict__ Bm,
                                                 const float* __restrict__ bias,
                                                 unsigned short* __restrict__ outb,
                                                 unsigned short* __restrict__ vtb,
                                                 float* __restrict__ psum,
                                                 float* __restrict__ outf,
                                                 unsigned int* __restrict__ mm) {
    __shared__ __align__(16) unsigned short Asm[2][8192];  // [buf][128 rows x 64 shorts]
    __shared__ __align__(16) unsigned short Bsm[2][8192];  // [buf][128 rows x 64 shorts]
    const size_t AKT = (size_t)M_ * 64;    // shorts per A k-block
    const size_t BKT = (size_t)1024 * 64;  // shorts per B k-block
    int tid = threadIdx.x, lane = tid & 63, wv = tid >> 6;
    int wm = wv >> 1, wn = wv & 1;
    int m0 = blockIdx.x * 128, n0 = blockIdx.y * 128;
    int lrow = lane & 15, lgrp = lane >> 4, sw = lane & 7;
    int r8 = lane >> 3, ch = lane & 7;
    // pre-swizzled blocked sources: lane covers (row = i*32 + wv*8 + r8, 16B chunk = ch ^ r8)
    const unsigned short* Ag = A + (size_t)(m0 + wv * 8 + r8) * 64 + ((ch ^ r8) << 3);
    const unsigned short* Bg = Bm + (size_t)(n0 + wv * 8 + r8) * 64 + ((ch ^ r8) << 3);

#define STAGE(buf, tt)                                                                        \
    {                                                                                         \
        _Pragma("unroll") for (int i = 0; i < 4; ++i)                                         \
            gload16(Ag + (size_t)(tt)*AKT + (size_t)(i * 32) * 64,                            \
                    &Asm[buf][(i * 32 + wv * 8) * 64]);                                       \
        _Pragma("unroll") for (int i = 0; i < 4; ++i)                                         \
            gload16(Bg + (size_t)(tt)*BKT + (size_t)(i * 32) * 64,                            \
                    &Bsm[buf][(i * 32 + wv * 8) * 64]);                                       \
    }
#define COMPUTE(buf)                                                                        \
    {                                                                                       \
        _Pragma("unroll") for (int kh = 0; kh < 2; ++kh) {                                  \
            int cp = (((kh << 2) | lgrp) ^ sw) << 3;                                        \
            bf16x8 af[4], bfr[4];                                                           \
            _Pragma("unroll") for (int mt = 0; mt < 4; ++mt)                                \
                af[mt] = *(const bf16x8*)&Asm[buf][(wm * 64 + mt * 16 + lrow) * 64 + cp];   \
            _Pragma("unroll") for (int nt = 0; nt < 4; ++nt)                                \
                bfr[nt] = *(const bf16x8*)&Bsm[buf][(wn * 64 + nt * 16 + lrow) * 64 + cp];  \
            _Pragma("unroll") for (int mt = 0; mt < 4; ++mt)                                \
                _Pragma("unroll") for (int nt = 0; nt < 4; ++nt)                            \
                    acc[mt][nt] = mfma16(af[mt], bfr[nt], acc[mt][nt]);                     \
        }                                                                                   \
    }

    f32x4 acc[4][4];
#pragma unroll
    for (int i = 0; i < 4; ++i)
#pragma unroll
        for (int j = 0; j < 4; ++j) acc[i][j] = (f32x4){0.f, 0.f, 0.f, 0.f};

    STAGE(0, 0);
    STAGE(1, 1);
    for (int t = 0; t < 15; ++t) {
        asm volatile("s_waitcnt vmcnt(8)" ::: "memory");  // buf[t&1] landed; t+1's 8 stay in flight
        __builtin_amdgcn_s_barrier();
        __builtin_amdgcn_sched_barrier(0);
        COMPUTE(t & 1);
        asm volatile("s_waitcnt lgkmcnt(0)" ::: "memory");  // my reads done before overwrite
        __builtin_amdgcn_s_barrier();
        __builtin_amdgcn_sched_barrier(0);
        if (t < 14) STAGE(t & 1, t + 2);
    }
    asm volatile("s_waitcnt vmcnt(0)" ::: "memory");
    __builtin_amdgcn_s_barrier();
    __builtin_amdgcn_sched_barrier(0);
    COMPUTE(1);
#undef STAGE
#undef COMPUTE

    float vmin = 1e30f, vmax = -1e30f;
#pragma unroll
    for (int nt = 0; nt < 4; ++nt) {
        int ncol = n0 + wn * 64 + nt * 16 + lrow;
        float bs = bias[ncol];
        float cs0 = 0.f, cs1 = 0.f;  // 32-row chunk partial sums (fused scan1)
#pragma unroll
        for (int mt = 0; mt < 4; ++mt) {
            unsigned int lo = 0, hi = 0;
#pragma unroll
            for (int r = 0; r < 4; ++r) {
                int mrow = m0 + wm * 64 + mt * 16 + lgrp * 4 + r;
                float val = acc[mt][nt][r] + bs;
                if constexpr (MODE == 0) {
                    vmin = fminf(vmin, val);
                    vmax = fmaxf(vmax, val);
                    if (mt < 2) cs0 += val; else cs1 += val;
                    int b = mrow >> 11, s = mrow & 2047, h = ncol >> 6, d = ncol & 63;
                    unsigned short bfv = f2bf(val);
                    outb[(size_t)((b * 16 + h) * 2048 + s) * 64 + d] = bfv;
                    if (r < 2) lo |= ((unsigned int)bfv) << (16 * r);
                    else       hi |= ((unsigned int)bfv) << (16 * (r - 2));
                } else {
                    outf[(size_t)mrow * 1024 + ncol] = val;
                }
            }
            if constexpr (MODE == 0) {  // fused transpose write: 4 consecutive s at fixed d
                int mrow0 = m0 + wm * 64 + mt * 16 + lgrp * 4;
                int b = mrow0 >> 11, s0 = mrow0 & 2047;
                int h = ncol >> 6, d = ncol & 63;
                uint2 pk; pk.x = lo; pk.y = hi;
                *(uint2*)&vtb[((size_t)(b * 16 + h) * 64 + d) * 2048 + s0] = pk;
            }
        }
        if constexpr (MODE == 0) {  // reduce 32-row chunk sums across the 4 lgrp groups
            cs0 += __shfl_xor(cs0, 16);
            cs0 += __shfl_xor(cs0, 32);
            cs1 += __shfl_xor(cs1, 16);
            cs1 += __shfl_xor(cs1, 32);
            if (lgrp == 0) {
                int b = m0 >> 11, h = ncol >> 6, d = ncol & 63;
                int bh = b * 16 + h;
                int c0 = ((m0 & 2047) >> 5) + wm * 2;
                psum[((size_t)bh * 64 + c0) * 64 + d] = cs0;
                psum[((size_t)bh * 64 + c0 + 1) * 64 + d] = cs1;
            }
        }
    }
    if constexpr (MODE == 0) {
#pragma unroll
        for (int m = 1; m < 64; m <<= 1) {
            vmin = fminf(vmin, __shfl_xor(vmin, m));
            vmax = fmaxf(vmax, __shfl_xor(vmax, m));
        }
        if (lane == 0) {
            int b = m0 >> 11;
            atomicMin(&mm[b * 2], fenc(vmin));
            atomicMax(&mm[b * 2 + 1], fenc(vmax));
        }
    }
}

// pass 2: one thread per (bh,d); register scan of 64 chunk sums -> exclusive base[bh][c][d]
__global__ __launch_bounds__(64) void k_scan2(const float* __restrict__ ps,
                                              float* __restrict__ base) {
    int bh = blockIdx.x;
    int d = threadIdx.x;
    const float* p = ps + (size_t)bh * 64 * 64 + d;
    float* bo = base + (size_t)bh * 64 * 64 + d;
    float vals[64];
#pragma unroll
    for (int c = 0; c < 64; ++c) vals[c] = p[(size_t)c * 64];
    float run = 0.f;
#pragma unroll
    for (int c = 0; c < 64; ++c) {
        float t = vals[c];
        vals[c] = run;
        run += t;
    }
#pragma unroll
    for (int c = 0; c < 64; ++c) bo[(size_t)c * 64] = vals[c];
}

// pass 3: one wave per (bh, chunk); resume scan from base, fuse rowsum -> gene directly.
// gene = inv / rowsum(inv) * ir * log2e  (ir folded; log2e folded so attn uses exp2;
// min-shift cancels in softmax)
__global__ __launch_bounds__(256) void k_scan3(const unsigned short* __restrict__ vb,
                                               const float* __restrict__ base,
                                               unsigned short* __restrict__ gene,
                                               const unsigned int* __restrict__ mm) {
    int g = blockIdx.x * 4 + (threadIdx.x >> 6);
    int d = threadIdx.x & 63;
    int bh = g >> 6, c = g & 63;
    int b = bh >> 4;
    float vmin = fdec(mm[b * 2]), vmax = fdec(mm[b * 2 + 1]);
    float ir = __fdividef(1.0f, vmax - vmin + 1e-8f);
    float irl = ir * 1.4426950408889634f;
    const unsigned short* src = vb + (size_t)bh * S_ * 64 + (size_t)c * 32 * 64 + d;
    unsigned short* dst = gene + (size_t)bh * S_ * 64 + (size_t)c * 32 * 64 + d;
    float acc = base[(size_t)g * 64 + d];
#pragma unroll 4
    for (int i = 0; i < 32; ++i) {
        int s = c * 32 + i;
        acc += bf2f(src[(size_t)i * 64]);
        float phi = __fdividef(acc, (float)(s + 1));
        float inv = __fdividef(1.0f, (phi - vmin) * ir + 0.5f);
        float rs = inv;
#pragma unroll
        for (int m = 1; m < 64; m <<= 1) rs += __shfl_xor(rs, m);
        dst[(size_t)i * 64] = f2bf(__fdividef(inv, rs) * irl);
    }
}

// Fixed-max flash attention v5: uniform small blocks for occupancy + backfill.
// Block = 4 waves x 16 query rows = 64 rows of one bh; key tile = 64. ALL waves share the
// SAME key range (njt = qt+1, uniform in block - no idle waves). Grid = 1024 longest-first
// -> 4 blocks/CU resident (LDS 40 KB) with backfill. Depth-1 DMA prefetch, ONE barrier/tile.
// QK swapped: mfma(A=v_j, B=gene_i) -> lane holds P[j=4lgrp+r][i=lrow]; cvt_pk -> uint2
// swizzled P^T writes, read b128 as PV's B-operand: out^T = mfma(T_d, P^T).
// p = exp2(s - C2) fixed shift: no running max; denom = per-lane sum + 2 shuffles.
// OUTPUT: K-blocked a_p[h][m][64] (kt == h since E-block 64 == head dim) for the wo gemm.
__global__ __launch_bounds__(256, 4) void k_attn(const unsigned short* __restrict__ gene,
                                                 const unsigned short* __restrict__ vb,
                                                 const unsigned short* __restrict__ vt,
                                                 unsigned short* __restrict__ attn_out,
                                                 const unsigned int* __restrict__ mm) {
    __shared__ __align__(16) unsigned short Vsm[2][4096];   // [buf][j 64][d 64] linear
    __shared__ __align__(16) unsigned short Tsm[2][4096];   // [buf][d 64][j 64] linear
    __shared__ __align__(16) unsigned short plds[4][1024];  // per-wave P^T [i 16][j 64] swz
    int tid = threadIdx.x, lane = tid & 63, w = tid >> 6;
    int bid = blockIdx.x;
    int qt = 31 - (bid >> 5);                      // 64-row q tile, longest first
    int bh = ((bid & 7) << 2) | ((bid >> 3) & 3);  // XCD-major bh
    int i0 = qt * 64 + w * 16;
    int lrow = lane & 15, lgrp = lane >> 4;
    int sx = lrow & 7;
    int r8 = lane >> 3, ch = lane & 7;

    int b = bh >> 4;
    float vmin = fdec(mm[b * 2]), vmax = fdec(mm[b * 2 + 1]);
    float ir = __fdividef(1.0f, vmax - vmin + 1e-8f);
    float C2 = (vmin * ir + 1.0f) * 1.4426950408889634f;  // fixed softmax shift, log2 domain

    const unsigned short* gbase = gene + (size_t)bh * S_ * 64;
    const unsigned short* vbase = vb + (size_t)bh * S_ * 64;
    const unsigned short* tbase = vt + (size_t)bh * 64 * S_;

    // DMA staging sources (pre-swizzled chunk)
    const unsigned short* Vg = vbase + (size_t)(w * 8 + r8) * 64 + ((ch ^ r8) << 3);
    const unsigned short* Tg = tbase + (size_t)(w * 8 + r8) * S_ + ((ch ^ r8) << 3);

#define ASTAGE(buf, jt_)                                                                  \
    {                                                                                     \
        int j0s = (jt_) << 6;                                                             \
        _Pragma("unroll") for (int i = 0; i < 2; ++i)                                     \
            gload16(Vg + (size_t)(j0s + i * 32) * 64, &Vsm[buf][(i * 32 + w * 8) * 64]);  \
        _Pragma("unroll") for (int i = 0; i < 2; ++i)                                     \
            gload16(Tg + (size_t)(i * 32) * S_ + j0s, &Tsm[buf][(i * 32 + w * 8) * 64]);  \
    }

    bf16x8 ga0 = *(const bf16x8*)(gbase + (size_t)(i0 + lrow) * 64 + lgrp * 8);
    bf16x8 ga1 = *(const bf16x8*)(gbase + (size_t)(i0 + lrow) * 64 + 32 + lgrp * 8);

    f32x4 acc[4];
#pragma unroll
    for (int dn = 0; dn < 4; ++dn) acc[dn] = (f32x4){0.f, 0.f, 0.f, 0.f};
    float lsum = 0.f;

    int njt = qt + 1;  // uniform across the block's 4 waves
    ASTAGE(0, 0);
    for (int jt = 0; jt < njt; ++jt) {
        int cur = jt & 1;
        asm volatile("s_waitcnt vmcnt(0)" ::: "memory");  // tile jt landed (issued 1 compute ago)
        __builtin_amdgcn_s_barrier();   // all waves consumed buf[(jt-1)&1] reads in iter jt-1
        __builtin_amdgcn_sched_barrier(0);
        if (jt + 1 < njt) ASTAGE(cur ^ 1, jt + 1);  // safe: that buf's reads done
        int j0 = jt << 6;
        __builtin_amdgcn_s_setprio(1);
        // ---- swapped scores: D[j=4lgrp+r][i=lrow] ----
        f32x4 Sv[4];
#pragma unroll
        for (int n = 0; n < 4; ++n) {
            const unsigned short* vr = &Vsm[cur][(n * 16 + lrow) * 64];
            bf16x8 a0 = *(const bf16x8*)(vr + ((lgrp ^ sx) << 3));
            bf16x8 a1 = *(const bf16x8*)(vr + (((lgrp + 4) ^ sx) << 3));
            f32x4 c = (f32x4){0.f, 0.f, 0.f, 0.f};
            c = mfma16(a0, ga0, c);
            c = mfma16(a1, ga1, c);
            Sv[n] = c;
        }
        bool tail = (jt == njt - 1);
        // ---- p = exp2(s - C2); per-lane denom; pack; swizzled 8B P^T writes ----
#pragma unroll
        for (int n = 0; n < 4; ++n) {
            float q0 = exp2f(Sv[n][0] - C2);
            float q1 = exp2f(Sv[n][1] - C2);
            float q2 = exp2f(Sv[n][2] - C2);
            float q3 = exp2f(Sv[n][3] - C2);
            if (tail) {
                int ii = i0 + lrow;
                int jj = j0 + n * 16 + 4 * lgrp;
                q0 = (jj     <= ii) ? q0 : 0.f;
                q1 = (jj + 1 <= ii) ? q1 : 0.f;
                q2 = (jj + 2 <= ii) ? q2 : 0.f;
                q3 = (jj + 3 <= ii) ? q3 : 0.f;
            }
            lsum += (q0 + q1) + (q2 + q3);
            uint2 pk;
            pk.x = cvt_pk_bf16(q0, q1);
            pk.y = cvt_pk_bf16(q2, q3);
            int chunk = 2 * n + (lgrp >> 1);
            *(uint2*)&plds[w][lrow * 64 + ((chunk ^ sx) << 3) + ((lgrp & 1) << 2)] = pk;
        }
        // wave-local LDS RAW: DS ops in-order per wave; compiler inserts lgkmcnt.
        // ---- PV^T: acc[dn] += T(16d x 32j) * P^T(16i x 32j) ----
#pragma unroll
        for (int chk = 0; chk < 2; ++chk) {
            int pc = ((chk * 4 + lgrp) ^ sx) << 3;
            bf16x8 pa = *(const bf16x8*)&plds[w][lrow * 64 + pc];
#pragma unroll
            for (int dn = 0; dn < 4; ++dn) {
                bf16x8 tf = *(const bf16x8*)&Tsm[cur][(dn * 16 + lrow) * 64 + pc];
                acc[dn] = mfma16(tf, pa, acc[dn]);
            }
        }
        __builtin_amdgcn_s_setprio(0);
    }
#undef ASTAGE
    // denominator: sum across the 4 lgrp groups (j-partials)
    lsum += __shfl_xor(lsum, 16);
    lsum += __shfl_xor(lsum, 32);
    lsum = __fdividef(1.0f, lsum);
    int bb = bh >> 4, h = bh & 15;
    int ii = i0 + lrow;
#pragma unroll
    for (int dn = 0; dn < 4; ++dn) {
        uint2 pk;
        pk.x = cvt_pk_bf16(acc[dn][0] * lsum, acc[dn][1] * lsum);
        pk.y = cvt_pk_bf16(acc[dn][2] * lsum, acc[dn][3] * lsum);
        // K-blocked output: a_p[kt=h][m=bb*S_+ii][64] at offset dn*16 + lgrp*4
        *(uint2*)&attn_out[((size_t)h * M_ + bb * S_ + ii) * 64 + dn * 16 + lgrp * 4] = pk;
    }
}

extern "C" void kernel_launch(void* const* d_in, const int* in_sizes, int n_in,
                              void* d_out, int out_size, void* d_ws, size_t ws_size,
                              hipStream_t stream) {
    const float* x = (const float*)d_in[0];
    const float* wv_w = (const float*)d_in[1];
    const float* wv_b = (const float*)d_in[2];
    const float* wo_w = (const float*)d_in[3];
    const float* wo_b = (const float*)d_in[4];
    float* out = (float*)d_out;

    char* w = (char*)d_ws;
    unsigned short* x_bf = (unsigned short*)(w);               // 8 MB  blocked [16][4096][64]
    unsigned short* wv_bf = (unsigned short*)(w + 8388608);    // 2 MB  blocked [16][1024][64]
    unsigned short* wo_bf = (unsigned short*)(w + 10485760);   // 2 MB  blocked [16][1024][64]
    unsigned short* v_bf = (unsigned short*)(w + 12582912);    // 8 MB  [b][h][s][d]
    unsigned short* vt_bf = (unsigned short*)(w + 20971520);   // 8 MB  [b][h][d][s]
    float* ps = (float*)(w + 29360128);                        // 512 KB [bh][c][d]
    float* base = (float*)(w + 29884416);                      // 512 KB [bh][c][d]
    unsigned short* gene = (unsigned short*)(w + 46137344);    // 8 MB
    unsigned short* a_bf = (unsigned short*)(w + 54525952);    // 8 MB  blocked [16][4096][64]
    unsigned int* mm = (unsigned int*)(w + 62914560);          // 16 B
    if (ws_size < 62914576) return;  // insufficient workspace -> fail loudly

    k_prep<<<3072, 256, 0, stream>>>(x, wv_w, wo_w, x_bf, wv_bf, wo_bf, mm);
    k_gemm<0><<<dim3(32, 8), 256, 0, stream>>>(x_bf, wv_bf, wv_b, v_bf, vt_bf, ps, nullptr, mm);
    k_scan2<<<32, 64, 0, stream>>>(ps, base);
    k_scan3<<<512, 256, 0, stream>>>(v_bf, base, gene, mm);
    k_attn<<<1024, 256, 0, stream>>>(gene, v_bf, vt_bf, a_bf, mm);
    k_gemm<1><<<dim3(32, 8), 256, 0, stream>>>(a_bf, wo_bf, wo_b, nullptr, nullptr, nullptr, out, nullptr);
}

// Round 20
// 125.293 us; speedup vs baseline: 1.6079x; 1.0407x over previous
//
#include <hip/hip_runtime.h>
#include <hip/hip_bf16.h>

#define B_ 2
#define S_ 2048
#define E_ 1024
#define H_ 16
#define D_ 64
#define M_ 4096  // B_*S_

typedef __bf16 bf16_t;
typedef bf16_t bf16x8 __attribute__((ext_vector_type(8)));
typedef float f32x4 __attribute__((ext_vector_type(4)));
typedef unsigned int u32;

__device__ __forceinline__ f32x4 mfma16(bf16x8 a, bf16x8 b, f32x4 c) {
    return __builtin_amdgcn_mfma_f32_16x16x32_bf16(a, b, c, 0, 0, 0);
}
__device__ __forceinline__ unsigned short f2bf(float f) {
    unsigned int u = __float_as_uint(f);
    unsigned int r = (u + 0x7fffu + ((u >> 16) & 1u)) >> 16;
    return (unsigned short)r;
}
__device__ __forceinline__ float bf2f(unsigned short s) {
    return __uint_as_float(((unsigned int)s) << 16);
}
// pack two f32 -> dword of 2 bf16 (src0 -> low half), RTNE
__device__ __forceinline__ u32 cvt_pk_bf16(float lo, float hi) {
    u32 r;
    asm("v_cvt_pk_bf16_f32 %0, %1, %2" : "=v"(r) : "v"(lo), "v"(hi));
    return r;
}
// order-preserving float<->uint for atomic min/max
__device__ __forceinline__ unsigned int fenc(float x) {
    unsigned int u = __float_as_uint(x);
    return (u & 0x80000000u) ? ~u : (u | 0x80000000u);
}
__device__ __forceinline__ float fdec(unsigned int u) {
    return __uint_as_float((u & 0x80000000u) ? (u ^ 0x80000000u) : ~u);
}
// async global->LDS DMA, 16B per lane; LDS dest = wave-uniform base + lane*16
__device__ __forceinline__ void gload16(const void* g, void* l) {
    __builtin_amdgcn_global_load_lds((const __attribute__((address_space(1))) u32*)g,
                                     (__attribute__((address_space(3))) u32*)l, 16, 0, 0);
}

// fused prep: cast x/wv/wo (f32 -> bf16, K-BLOCKED [16][rows][64]) + init min/max atomics.
// blocks 0..2047: x (4096 rows); 2048..2559: wv; 2560..3071: wo.
__global__ __launch_bounds__(256) void k_prep(const float* __restrict__ x,
                                              const float* __restrict__ wv,
                                              const float* __restrict__ wo,
                                              unsigned short* __restrict__ xd,
                                              unsigned short* __restrict__ wvd,
                                              unsigned short* __restrict__ wod,
                                              unsigned int* __restrict__ mm) {
    int bid = blockIdx.x, tid = threadIdx.x;
    if (bid == 0 && tid < 2) { mm[tid * 2] = 0xFFFFFFFFu; mm[tid * 2 + 1] = 0u; }
    const float* src;
    unsigned short* dst;
    int i, rows;
    if (bid < 2048) { src = x;  dst = xd;  i = bid * 256 + tid;          rows = 4096; }
    else if (bid < 2560) { src = wv; dst = wvd; i = (bid - 2048) * 256 + tid; rows = 1024; }
    else { src = wo; dst = wod; i = (bid - 2560) * 256 + tid; rows = 1024; }
    int m = (i * 8) >> 10, k = (i * 8) & 1023;
    int kt = k >> 6, ko = k & 63;
    const float4* s4 = (const float4*)src;
    float4 a = s4[2 * i], c = s4[2 * i + 1];
    uint4 o;
    o.x = cvt_pk_bf16(a.x, a.y);
    o.y = cvt_pk_bf16(a.z, a.w);
    o.z = cvt_pk_bf16(c.x, c.y);
    o.w = cvt_pk_bf16(c.z, c.w);
    *(uint4*)&dst[((size_t)kt * rows + m) * 64 + ko] = o;
}

// C[m][n] = sum_k A[m][k]*B[n][k] + bias[n].  A blocked [16][4096][64], B blocked [16][1024][64].
// BK=128 variant: 8 K-steps (half the rendezvous of r13/r19 - per-step cost measured ~7.7k cy
// is fixed-overhead dominated, so fewer steps = less total stall; occupancy already 1 block/CU
// so m132's occupancy penalty doesn't apply). 128x128 tile, 4 waves (64x64), LDS 128 KB
// (2 buf x 64 KB = 2 kt-blocks of A+B), counted vmcnt(16), 2 barriers/step.
// Blocked layouts give 1KB-contiguous staging. Swizzle: pre-swizzled GLOBAL source
// (chunk ^= row&7), same XOR on ds_read; LDS writes linear.
// MODE 0: bf16 v [b][h][s][d] + vt [b][h][d][s] + min/max atomics + fused scan1 chunk sums.
// MODE 1: fp32 outf[m][n].
template <int MODE>
__global__ __launch_bounds__(256, 1) void k_gemm(const unsigned short* __restrict__ A,
                                                 const unsigned short* __restrict__ Bm,
                                                 const float* __restrict__ bias,
                                                 unsigned short* __restrict__ outb,
                                                 unsigned short* __restrict__ vtb,
                                                 float* __restrict__ psum,
                                                 float* __restrict__ outf,
                                                 unsigned int* __restrict__ mm) {
    __shared__ __align__(16) unsigned short Asm[2][16384];  // [buf][2 kt][128 rows][64]
    __shared__ __align__(16) unsigned short Bsm[2][16384];  // [buf][2 kt][128 rows][64]
    const size_t AKT = (size_t)M_ * 64;    // shorts per A k-block (kt granularity = 64 k)
    const size_t BKT = (size_t)1024 * 64;  // shorts per B k-block
    int tid = threadIdx.x, lane = tid & 63, wv = tid >> 6;
    int wm = wv >> 1, wn = wv & 1;
    int m0 = blockIdx.x * 128, n0 = blockIdx.y * 128;
    int lrow = lane & 15, lgrp = lane >> 4, sw = lane & 7;
    int r8 = lane >> 3, ch = lane & 7;
    // pre-swizzled blocked sources: lane covers (row = i*32 + wv*8 + r8, 16B chunk = ch ^ r8)
    const unsigned short* Ag = A + (size_t)(m0 + wv * 8 + r8) * 64 + ((ch ^ r8) << 3);
    const unsigned short* Bg = Bm + (size_t)(n0 + wv * 8 + r8) * 64 + ((ch ^ r8) << 3);

#define STAGE(buf, tt)                                                                        \
    {                                                                                         \
        _Pragma("unroll") for (int k2 = 0; k2 < 2; ++k2)                                      \
            _Pragma("unroll") for (int i = 0; i < 4; ++i)                                     \
                gload16(Ag + (size_t)(2 * (tt) + k2) * AKT + (size_t)(i * 32) * 64,           \
                        &Asm[buf][k2 * 8192 + (i * 32 + wv * 8) * 64]);                       \
        _Pragma("unroll") for (int k2 = 0; k2 < 2; ++k2)                                      \
            _Pragma("unroll") for (int i = 0; i < 4; ++i)                                     \
                gload16(Bg + (size_t)(2 * (tt) + k2) * BKT + (size_t)(i * 32) * 64,           \
                        &Bsm[buf][k2 * 8192 + (i * 32 + wv * 8) * 64]);                       \
    }
#define COMPUTE(buf)                                                                          \
    {                                                                                         \
        _Pragma("unroll") for (int kh = 0; kh < 4; ++kh) {                                    \
            int kb = (kh >> 1) * 8192;                                                        \
            int cp = ((((kh & 1) << 2) | lgrp) ^ sw) << 3;                                    \
            bf16x8 af[4], bfr[4];                                                             \
            _Pragma("unroll") for (int mt = 0; mt < 4; ++mt)                                  \
                af[mt] = *(const bf16x8*)&Asm[buf][kb + (wm * 64 + mt * 16 + lrow) * 64 + cp];\
            _Pragma("unroll") for (int nt = 0; nt < 4; ++nt)                                  \
                bfr[nt] = *(const bf16x8*)&Bsm[buf][kb + (wn * 64 + nt * 16 + lrow) * 64 + cp];\
            _Pragma("unroll") for (int mt = 0; mt < 4; ++mt)                                  \
                _Pragma("unroll") for (int nt = 0; nt < 4; ++nt)                              \
                    acc[mt][nt] = mfma16(af[mt], bfr[nt], acc[mt][nt]);                       \
        }                                                                                     \
    }

    f32x4 acc[4][4];
#pragma unroll
    for (int i = 0; i < 4; ++i)
#pragma unroll
        for (int j = 0; j < 4; ++j) acc[i][j] = (f32x4){0.f, 0.f, 0.f, 0.f};

    STAGE(0, 0);
    STAGE(1, 1);
    for (int t = 0; t < 8; ++t) {
        if (t < 7) {
            asm volatile("s_waitcnt vmcnt(16)" ::: "memory");  // step t landed; t+1's 16 in flight
        } else {
            asm volatile("s_waitcnt vmcnt(0)" ::: "memory");
        }
        __builtin_amdgcn_s_barrier();
        __builtin_amdgcn_sched_barrier(0);
        __builtin_amdgcn_s_setprio(1);
        COMPUTE(t & 1);
        __builtin_amdgcn_s_setprio(0);
        asm volatile("s_waitcnt lgkmcnt(0)" ::: "memory");  // my reads done before overwrite
        __builtin_amdgcn_s_barrier();
        __builtin_amdgcn_sched_barrier(0);
        if (t < 6) STAGE(t & 1, t + 2);
    }
#undef STAGE
#undef COMPUTE

    float vmin = 1e30f, vmax = -1e30f;
#pragma unroll
    for (int nt = 0; nt < 4; ++nt) {
        int ncol = n0 + wn * 64 + nt * 16 + lrow;
        float bs = bias[ncol];
        float cs0 = 0.f, cs1 = 0.f;  // 32-row chunk partial sums (fused scan1)
#pragma unroll
        for (int mt = 0; mt < 4; ++mt) {
            unsigned int lo = 0, hi = 0;
#pragma unroll
            for (int r = 0; r < 4; ++r) {
                int mrow = m0 + wm * 64 + mt * 16 + lgrp * 4 + r;
                float val = acc[mt][nt][r] + bs;
                if constexpr (MODE == 0) {
                    vmin = fminf(vmin, val);
                    vmax = fmaxf(vmax, val);
                    if (mt < 2) cs0 += val; else cs1 += val;
                    int b = mrow >> 11, s = mrow & 2047, h = ncol >> 6, d = ncol & 63;
                    unsigned short bfv = f2bf(val);
                    outb[(size_t)((b * 16 + h) * 2048 + s) * 64 + d] = bfv;
                    if (r < 2) lo |= ((unsigned int)bfv) << (16 * r);
                    else       hi |= ((unsigned int)bfv) << (16 * (r - 2));
                } else {
                    outf[(size_t)mrow * 1024 + ncol] = val;
                }
            }
            if constexpr (MODE == 0) {  // fused transpose write: 4 consecutive s at fixed d
                int mrow0 = m0 + wm * 64 + mt * 16 + lgrp * 4;
                int b = mrow0 >> 11, s0 = mrow0 & 2047;
                int h = ncol >> 6, d = ncol & 63;
                uint2 pk; pk.x = lo; pk.y = hi;
                *(uint2*)&vtb[((size_t)(b * 16 + h) * 64 + d) * 2048 + s0] = pk;
            }
        }
        if constexpr (MODE == 0) {  // reduce 32-row chunk sums across the 4 lgrp groups
            cs0 += __shfl_xor(cs0, 16);
            cs0 += __shfl_xor(cs0, 32);
            cs1 += __shfl_xor(cs1, 16);
            cs1 += __shfl_xor(cs1, 32);
            if (lgrp == 0) {
                int b = m0 >> 11, h = ncol >> 6, d = ncol & 63;
                int bh = b * 16 + h;
                int c0 = ((m0 & 2047) >> 5) + wm * 2;
                psum[((size_t)bh * 64 + c0) * 64 + d] = cs0;
                psum[((size_t)bh * 64 + c0 + 1) * 64 + d] = cs1;
            }
        }
    }
    if constexpr (MODE == 0) {
#pragma unroll
        for (int m = 1; m < 64; m <<= 1) {
            vmin = fminf(vmin, __shfl_xor(vmin, m));
            vmax = fmaxf(vmax, __shfl_xor(vmax, m));
        }
        if (lane == 0) {
            int b = m0 >> 11;
            atomicMin(&mm[b * 2], fenc(vmin));
            atomicMax(&mm[b * 2 + 1], fenc(vmax));
        }
    }
}

// pass 2: one thread per (bh,d); register scan of 64 chunk sums -> exclusive base[bh][c][d]
__global__ __launch_bounds__(64) void k_scan2(const float* __restrict__ ps,
                                              float* __restrict__ base) {
    int bh = blockIdx.x;
    int d = threadIdx.x;
    const float* p = ps + (size_t)bh * 64 * 64 + d;
    float* bo = base + (size_t)bh * 64 * 64 + d;
    float vals[64];
#pragma unroll
    for (int c = 0; c < 64; ++c) vals[c] = p[(size_t)c * 64];
    float run = 0.f;
#pragma unroll
    for (int c = 0; c < 64; ++c) {
        float t = vals[c];
        vals[c] = run;
        run += t;
    }
#pragma unroll
    for (int c = 0; c < 64; ++c) bo[(size_t)c * 64] = vals[c];
}

// pass 3: one wave per (bh, chunk); resume scan from base, fuse rowsum -> gene directly.
// gene = inv / rowsum(inv) * ir * log2e  (ir folded; log2e folded so attn uses exp2;
// min-shift cancels in softmax)
__global__ __launch_bounds__(256) void k_scan3(const unsigned short* __restrict__ vb,
                                               const float* __restrict__ base,
                                               unsigned short* __restrict__ gene,
                                               const unsigned int* __restrict__ mm) {
    int g = blockIdx.x * 4 + (threadIdx.x >> 6);
    int d = threadIdx.x & 63;
    int bh = g >> 6, c = g & 63;
    int b = bh >> 4;
    float vmin = fdec(mm[b * 2]), vmax = fdec(mm[b * 2 + 1]);
    float ir = __fdividef(1.0f, vmax - vmin + 1e-8f);
    float irl = ir * 1.4426950408889634f;
    const unsigned short* src = vb + (size_t)bh * S_ * 64 + (size_t)c * 32 * 64 + d;
    unsigned short* dst = gene + (size_t)bh * S_ * 64 + (size_t)c * 32 * 64 + d;
    float acc = base[(size_t)g * 64 + d];
#pragma unroll 4
    for (int i = 0; i < 32; ++i) {
        int s = c * 32 + i;
        acc += bf2f(src[(size_t)i * 64]);
        float phi = __fdividef(acc, (float)(s + 1));
        float inv = __fdividef(1.0f, (phi - vmin) * ir + 0.5f);
        float rs = inv;
#pragma unroll
        for (int m = 1; m < 64; m <<= 1) rs += __shfl_xor(rs, m);
        dst[(size_t)i * 64] = f2bf(__fdividef(inv, rs) * irl);
    }
}

// Fixed-max flash attention v5: uniform small blocks for occupancy + backfill.
// Block = 4 waves x 16 query rows = 64 rows of one bh; key tile = 64. ALL waves share the
// SAME key range (njt = qt+1, uniform in block - no idle waves). Grid = 1024 longest-first
// -> 4 blocks/CU resident (LDS 40 KB) with backfill. Depth-1 DMA prefetch, ONE barrier/tile.
// QK swapped: mfma(A=v_j, B=gene_i) -> lane holds P[j=4lgrp+r][i=lrow]; cvt_pk -> uint2
// swizzled P^T writes, read b128 as PV's B-operand: out^T = mfma(T_d, P^T).
// p = exp2(s - C2) fixed shift: no running max; denom = per-lane sum + 2 shuffles.
// OUTPUT: K-blocked a_p[h][m][64] (kt == h since E-block 64 == head dim) for the wo gemm.
__global__ __launch_bounds__(256, 4) void k_attn(const unsigned short* __restrict__ gene,
                                                 const unsigned short* __restrict__ vb,
                                                 const unsigned short* __restrict__ vt,
                                                 unsigned short* __restrict__ attn_out,
                                                 const unsigned int* __restrict__ mm) {
    __shared__ __align__(16) unsigned short Vsm[2][4096];   // [buf][j 64][d 64] linear
    __shared__ __align__(16) unsigned short Tsm[2][4096];   // [buf][d 64][j 64] linear
    __shared__ __align__(16) unsigned short plds[4][1024];  // per-wave P^T [i 16][j 64] swz
    int tid = threadIdx.x, lane = tid & 63, w = tid >> 6;
    int bid = blockIdx.x;
    int qt = 31 - (bid >> 5);                      // 64-row q tile, longest first
    int bh = ((bid & 7) << 2) | ((bid >> 3) & 3);  // XCD-major bh
    int i0 = qt * 64 + w * 16;
    int lrow = lane & 15, lgrp = lane >> 4;
    int sx = lrow & 7;
    int r8 = lane >> 3, ch = lane & 7;

    int b = bh >> 4;
    float vmin = fdec(mm[b * 2]), vmax = fdec(mm[b * 2 + 1]);
    float ir = __fdividef(1.0f, vmax - vmin + 1e-8f);
    float C2 = (vmin * ir + 1.0f) * 1.4426950408889634f;  // fixed softmax shift, log2 domain

    const unsigned short* gbase = gene + (size_t)bh * S_ * 64;
    const unsigned short* vbase = vb + (size_t)bh * S_ * 64;
    const unsigned short* tbase = vt + (size_t)bh * 64 * S_;

    // DMA staging sources (pre-swizzled chunk)
    const unsigned short* Vg = vbase + (size_t)(w * 8 + r8) * 64 + ((ch ^ r8) << 3);
    const unsigned short* Tg = tbase + (size_t)(w * 8 + r8) * S_ + ((ch ^ r8) << 3);

#define ASTAGE(buf, jt_)                                                                  \
    {                                                                                     \
        int j0s = (jt_) << 6;                                                             \
        _Pragma("unroll") for (int i = 0; i < 2; ++i)                                     \
            gload16(Vg + (size_t)(j0s + i * 32) * 64, &Vsm[buf][(i * 32 + w * 8) * 64]);  \
        _Pragma("unroll") for (int i = 0; i < 2; ++i)                                     \
            gload16(Tg + (size_t)(i * 32) * S_ + j0s, &Tsm[buf][(i * 32 + w * 8) * 64]);  \
    }

    bf16x8 ga0 = *(const bf16x8*)(gbase + (size_t)(i0 + lrow) * 64 + lgrp * 8);
    bf16x8 ga1 = *(const bf16x8*)(gbase + (size_t)(i0 + lrow) * 64 + 32 + lgrp * 8);

    f32x4 acc[4];
#pragma unroll
    for (int dn = 0; dn < 4; ++dn) acc[dn] = (f32x4){0.f, 0.f, 0.f, 0.f};
    float lsum = 0.f;

    int njt = qt + 1;  // uniform across the block's 4 waves
    ASTAGE(0, 0);
    for (int jt = 0; jt < njt; ++jt) {
        int cur = jt & 1;
        asm volatile("s_waitcnt vmcnt(0)" ::: "memory");  // tile jt landed (issued 1 compute ago)
        __builtin_amdgcn_s_barrier();   // all waves consumed buf[(jt-1)&1] reads in iter jt-1
        __builtin_amdgcn_sched_barrier(0);
        if (jt + 1 < njt) ASTAGE(cur ^ 1, jt + 1);  // safe: that buf's reads done
        int j0 = jt << 6;
        __builtin_amdgcn_s_setprio(1);
        // ---- swapped scores: D[j=4lgrp+r][i=lrow] ----
        f32x4 Sv[4];
#pragma unroll
        for (int n = 0; n < 4; ++n) {
            const unsigned short* vr = &Vsm[cur][(n * 16 + lrow) * 64];
            bf16x8 a0 = *(const bf16x8*)(vr + ((lgrp ^ sx) << 3));
            bf16x8 a1 = *(const bf16x8*)(vr + (((lgrp + 4) ^ sx) << 3));
            f32x4 c = (f32x4){0.f, 0.f, 0.f, 0.f};
            c = mfma16(a0, ga0, c);
            c = mfma16(a1, ga1, c);
            Sv[n] = c;
        }
        bool tail = (jt == njt - 1);
        // ---- p = exp2(s - C2); per-lane denom; pack; swizzled 8B P^T writes ----
#pragma unroll
        for (int n = 0; n < 4; ++n) {
            float q0 = exp2f(Sv[n][0] - C2);
            float q1 = exp2f(Sv[n][1] - C2);
            float q2 = exp2f(Sv[n][2] - C2);
            float q3 = exp2f(Sv[n][3] - C2);
            if (tail) {
                int ii = i0 + lrow;
                int jj = j0 + n * 16 + 4 * lgrp;
                q0 = (jj     <= ii) ? q0 : 0.f;
                q1 = (jj + 1 <= ii) ? q1 : 0.f;
                q2 = (jj + 2 <= ii) ? q2 : 0.f;
                q3 = (jj + 3 <= ii) ? q3 : 0.f;
            }
            lsum += (q0 + q1) + (q2 + q3);
            uint2 pk;
            pk.x = cvt_pk_bf16(q0, q1);
            pk.y = cvt_pk_bf16(q2, q3);
            int chunk = 2 * n + (lgrp >> 1);
            *(uint2*)&plds[w][lrow * 64 + ((chunk ^ sx) << 3) + ((lgrp & 1) << 2)] = pk;
        }
        // wave-local LDS RAW: DS ops in-order per wave; compiler inserts lgkmcnt.
        // ---- PV^T: acc[dn] += T(16d x 32j) * P^T(16i x 32j) ----
#pragma unroll
        for (int chk = 0; chk < 2; ++chk) {
            int pc = ((chk * 4 + lgrp) ^ sx) << 3;
            bf16x8 pa = *(const bf16x8*)&plds[w][lrow * 64 + pc];
#pragma unroll
            for (int dn = 0; dn < 4; ++dn) {
                bf16x8 tf = *(const bf16x8*)&Tsm[cur][(dn * 16 + lrow) * 64 + pc];
                acc[dn] = mfma16(tf, pa, acc[dn]);
            }
        }
        __builtin_amdgcn_s_setprio(0);
    }
#undef ASTAGE
    // denominator: sum across the 4 lgrp groups (j-partials)
    lsum += __shfl_xor(lsum, 16);
    lsum += __shfl_xor(lsum, 32);
    lsum = __fdividef(1.0f, lsum);
    int bb = bh >> 4, h = bh & 15;
    int ii = i0 + lrow;
#pragma unroll
    for (int dn = 0; dn < 4; ++dn) {
        uint2 pk;
        pk.x = cvt_pk_bf16(acc[dn][0] * lsum, acc[dn][1] * lsum);
        pk.y = cvt_pk_bf16(acc[dn][2] * lsum, acc[dn][3] * lsum);
        // K-blocked output: a_p[kt=h][m=bb*S_+ii][64] at offset dn*16 + lgrp*4
        *(uint2*)&attn_out[((size_t)h * M_ + bb * S_ + ii) * 64 + dn * 16 + lgrp * 4] = pk;
    }
}

extern "C" void kernel_launch(void* const* d_in, const int* in_sizes, int n_in,
                              void* d_out, int out_size, void* d_ws, size_t ws_size,
                              hipStream_t stream) {
    const float* x = (const float*)d_in[0];
    const float* wv_w = (const float*)d_in[1];
    const float* wv_b = (const float*)d_in[2];
    const float* wo_w = (const float*)d_in[3];
    const float* wo_b = (const float*)d_in[4];
    float* out = (float*)d_out;

    char* w = (char*)d_ws;
    unsigned short* x_bf = (unsigned short*)(w);               // 8 MB  blocked [16][4096][64]
    unsigned short* wv_bf = (unsigned short*)(w + 8388608);    // 2 MB  blocked [16][1024][64]
    unsigned short* wo_bf = (unsigned short*)(w + 10485760);   // 2 MB  blocked [16][1024][64]
    unsigned short* v_bf = (unsigned short*)(w + 12582912);    // 8 MB  [b][h][s][d]
    unsigned short* vt_bf = (unsigned short*)(w + 20971520);   // 8 MB  [b][h][d][s]
    float* ps = (float*)(w + 29360128);                        // 512 KB [bh][c][d]
    float* base = (float*)(w + 29884416);                      // 512 KB [bh][c][d]
    unsigned short* gene = (unsigned short*)(w + 46137344);    // 8 MB
    unsigned short* a_bf = (unsigned short*)(w + 54525952);    // 8 MB  blocked [16][4096][64]
    unsigned int* mm = (unsigned int*)(w + 62914560);          // 16 B
    if (ws_size < 62914576) return;  // insufficient workspace -> fail loudly

    k_prep<<<3072, 256, 0, stream>>>(x, wv_w, wo_w, x_bf, wv_bf, wo_bf, mm);
    k_gemm<0><<<dim3(32, 8), 256, 0, stream>>>(x_bf, wv_bf, wv_b, v_bf, vt_bf, ps, nullptr, mm);
    k_scan2<<<32, 64, 0, stream>>>(ps, base);
    k_scan3<<<512, 256, 0, stream>>>(v_bf, base, gene, mm);
    k_attn<<<1024, 256, 0, stream>>>(gene, v_bf, vt_bf, a_bf, mm);
    k_gemm<1><<<dim3(32, 8), 256, 0, stream>>>(a_bf, wo_bf, wo_b, nullptr, nullptr, nullptr, out, nullptr);
}

// Round 21
// 116.964 us; speedup vs baseline: 1.7224x; 1.0712x over previous
//
#include <hip/hip_runtime.h>
#include <hip/hip_bf16.h>

#define B_ 2
#define S_ 2048
#define E_ 1024
#define H_ 16
#define D_ 64
#define M_ 4096  // B_*S_

typedef __bf16 bf16_t;
typedef bf16_t bf16x8 __attribute__((ext_vector_type(8)));
typedef float f32x4 __attribute__((ext_vector_type(4)));
typedef unsigned int u32;

__device__ __forceinline__ f32x4 mfma16(bf16x8 a, bf16x8 b, f32x4 c) {
    return __builtin_amdgcn_mfma_f32_16x16x32_bf16(a, b, c, 0, 0, 0);
}
__device__ __forceinline__ unsigned short f2bf(float f) {
    unsigned int u = __float_as_uint(f);
    unsigned int r = (u + 0x7fffu + ((u >> 16) & 1u)) >> 16;
    return (unsigned short)r;
}
__device__ __forceinline__ float bf2f(unsigned short s) {
    return __uint_as_float(((unsigned int)s) << 16);
}
// pack two f32 -> dword of 2 bf16 (src0 -> low half), RTNE
__device__ __forceinline__ u32 cvt_pk_bf16(float lo, float hi) {
    u32 r;
    asm("v_cvt_pk_bf16_f32 %0, %1, %2" : "=v"(r) : "v"(lo), "v"(hi));
    return r;
}
// order-preserving float<->uint for atomic min/max
__device__ __forceinline__ unsigned int fenc(float x) {
    unsigned int u = __float_as_uint(x);
    return (u & 0x80000000u) ? ~u : (u | 0x80000000u);
}
__device__ __forceinline__ float fdec(unsigned int u) {
    return __uint_as_float((u & 0x80000000u) ? (u ^ 0x80000000u) : ~u);
}
// async global->LDS DMA, 16B per lane; LDS dest = wave-uniform base + lane*16
__device__ __forceinline__ void gload16(const void* g, void* l) {
    __builtin_amdgcn_global_load_lds((const __attribute__((address_space(1))) u32*)g,
                                     (__attribute__((address_space(3))) u32*)l, 16, 0, 0);
}

// fused prep: cast x/wv/wo (f32 -> bf16, K-BLOCKED [16][rows][64]) + init min/max atomics.
// blocks 0..2047: x (4096 rows); 2048..2559: wv; 2560..3071: wo.
__global__ __launch_bounds__(256) void k_prep(const float* __restrict__ x,
                                              const float* __restrict__ wv,
                                              const float* __restrict__ wo,
                                              unsigned short* __restrict__ xd,
                                              unsigned short* __restrict__ wvd,
                                              unsigned short* __restrict__ wod,
                                              unsigned int* __restrict__ mm) {
    int bid = blockIdx.x, tid = threadIdx.x;
    if (bid == 0 && tid < 2) { mm[tid * 2] = 0xFFFFFFFFu; mm[tid * 2 + 1] = 0u; }
    const float* src;
    unsigned short* dst;
    int i, rows;
    if (bid < 2048) { src = x;  dst = xd;  i = bid * 256 + tid;          rows = 4096; }
    else if (bid < 2560) { src = wv; dst = wvd; i = (bid - 2048) * 256 + tid; rows = 1024; }
    else { src = wo; dst = wod; i = (bid - 2560) * 256 + tid; rows = 1024; }
    int m = (i * 8) >> 10, k = (i * 8) & 1023;
    int kt = k >> 6, ko = k & 63;
    const float4* s4 = (const float4*)src;
    float4 a = s4[2 * i], c = s4[2 * i + 1];
    uint4 o;
    o.x = cvt_pk_bf16(a.x, a.y);
    o.y = cvt_pk_bf16(a.z, a.w);
    o.z = cvt_pk_bf16(c.x, c.y);
    o.w = cvt_pk_bf16(c.z, c.w);
    *(uint4*)&dst[((size_t)kt * rows + m) * 64 + ko] = o;
}

// C[m][n] = sum_k A[m][k]*B[n][k] + bias[n].  A blocked [16][4096][64], B blocked [16][1024][64].
// BK=128, 8 K-steps (r20-best): 128x128 tile, 4 waves (64x64), LDS 128 KB (2 buf x 2 kt-blocks),
// counted vmcnt(16), 2 barriers/step. Blocked layouts give 1KB-contiguous staging.
// Swizzle: pre-swizzled GLOBAL source (chunk ^= row&7), same XOR on ds_read; LDS linear.
// MODE 0: bf16 v [b][h][s][d] + vt [b][h][d][s] + min/max atomics + fused scan1 chunk sums.
// MODE 1: fp32 outf[m][n].
template <int MODE>
__global__ __launch_bounds__(256, 1) void k_gemm(const unsigned short* __restrict__ A,
                                                 const unsigned short* __restrict__ Bm,
                                                 const float* __restrict__ bias,
                                                 unsigned short* __restrict__ outb,
                                                 unsigned short* __restrict__ vtb,
                                                 float* __restrict__ psum,
                                                 float* __restrict__ outf,
                                                 unsigned int* __restrict__ mm) {
    __shared__ __align__(16) unsigned short Asm[2][16384];  // [buf][2 kt][128 rows][64]
    __shared__ __align__(16) unsigned short Bsm[2][16384];  // [buf][2 kt][128 rows][64]
    const size_t AKT = (size_t)M_ * 64;    // shorts per A k-block (kt granularity = 64 k)
    const size_t BKT = (size_t)1024 * 64;  // shorts per B k-block
    int tid = threadIdx.x, lane = tid & 63, wv = tid >> 6;
    int wm = wv >> 1, wn = wv & 1;
    int m0 = blockIdx.x * 128, n0 = blockIdx.y * 128;
    int lrow = lane & 15, lgrp = lane >> 4, sw = lane & 7;
    int r8 = lane >> 3, ch = lane & 7;
    // pre-swizzled blocked sources: lane covers (row = i*32 + wv*8 + r8, 16B chunk = ch ^ r8)
    const unsigned short* Ag = A + (size_t)(m0 + wv * 8 + r8) * 64 + ((ch ^ r8) << 3);
    const unsigned short* Bg = Bm + (size_t)(n0 + wv * 8 + r8) * 64 + ((ch ^ r8) << 3);

#define STAGE(buf, tt)                                                                        \
    {                                                                                         \
        _Pragma("unroll") for (int k2 = 0; k2 < 2; ++k2)                                      \
            _Pragma("unroll") for (int i = 0; i < 4; ++i)                                     \
                gload16(Ag + (size_t)(2 * (tt) + k2) * AKT + (size_t)(i * 32) * 64,           \
                        &Asm[buf][k2 * 8192 + (i * 32 + wv * 8) * 64]);                       \
        _Pragma("unroll") for (int k2 = 0; k2 < 2; ++k2)                                      \
            _Pragma("unroll") for (int i = 0; i < 4; ++i)                                     \
                gload16(Bg + (size_t)(2 * (tt) + k2) * BKT + (size_t)(i * 32) * 64,           \
                        &Bsm[buf][k2 * 8192 + (i * 32 + wv * 8) * 64]);                       \
    }
#define COMPUTE(buf)                                                                          \
    {                                                                                         \
        _Pragma("unroll") for (int kh = 0; kh < 4; ++kh) {                                    \
            int kb = (kh >> 1) * 8192;                                                        \
            int cp = ((((kh & 1) << 2) | lgrp) ^ sw) << 3;                                    \
            bf16x8 af[4], bfr[4];                                                             \
            _Pragma("unroll") for (int mt = 0; mt < 4; ++mt)                                  \
                af[mt] = *(const bf16x8*)&Asm[buf][kb + (wm * 64 + mt * 16 + lrow) * 64 + cp];\
            _Pragma("unroll") for (int nt = 0; nt < 4; ++nt)                                  \
                bfr[nt] = *(const bf16x8*)&Bsm[buf][kb + (wn * 64 + nt * 16 + lrow) * 64 + cp];\
            _Pragma("unroll") for (int mt = 0; mt < 4; ++mt)                                  \
                _Pragma("unroll") for (int nt = 0; nt < 4; ++nt)                              \
                    acc[mt][nt] = mfma16(af[mt], bfr[nt], acc[mt][nt]);                       \
        }                                                                                     \
    }

    f32x4 acc[4][4];
#pragma unroll
    for (int i = 0; i < 4; ++i)
#pragma unroll
        for (int j = 0; j < 4; ++j) acc[i][j] = (f32x4){0.f, 0.f, 0.f, 0.f};

    STAGE(0, 0);
    STAGE(1, 1);
    for (int t = 0; t < 8; ++t) {
        if (t < 7) {
            asm volatile("s_waitcnt vmcnt(16)" ::: "memory");  // step t landed; t+1's 16 in flight
        } else {
            asm volatile("s_waitcnt vmcnt(0)" ::: "memory");
        }
        __builtin_amdgcn_s_barrier();
        __builtin_amdgcn_sched_barrier(0);
        __builtin_amdgcn_s_setprio(1);
        COMPUTE(t & 1);
        __builtin_amdgcn_s_setprio(0);
        asm volatile("s_waitcnt lgkmcnt(0)" ::: "memory");  // my reads done before overwrite
        __builtin_amdgcn_s_barrier();
        __builtin_amdgcn_sched_barrier(0);
        if (t < 6) STAGE(t & 1, t + 2);
    }
#undef STAGE
#undef COMPUTE

    float vmin = 1e30f, vmax = -1e30f;
#pragma unroll
    for (int nt = 0; nt < 4; ++nt) {
        int ncol = n0 + wn * 64 + nt * 16 + lrow;
        float bs = bias[ncol];
        float cs0 = 0.f, cs1 = 0.f;  // 32-row chunk partial sums (fused scan1)
#pragma unroll
        for (int mt = 0; mt < 4; ++mt) {
            unsigned int lo = 0, hi = 0;
#pragma unroll
            for (int r = 0; r < 4; ++r) {
                int mrow = m0 + wm * 64 + mt * 16 + lgrp * 4 + r;
                float val = acc[mt][nt][r] + bs;
                if constexpr (MODE == 0) {
                    vmin = fminf(vmin, val);
                    vmax = fmaxf(vmax, val);
                    if (mt < 2) cs0 += val; else cs1 += val;
                    int b = mrow >> 11, s = mrow & 2047, h = ncol >> 6, d = ncol & 63;
                    unsigned short bfv = f2bf(val);
                    outb[(size_t)((b * 16 + h) * 2048 + s) * 64 + d] = bfv;
                    if (r < 2) lo |= ((unsigned int)bfv) << (16 * r);
                    else       hi |= ((unsigned int)bfv) << (16 * (r - 2));
                } else {
                    outf[(size_t)mrow * 1024 + ncol] = val;
                }
            }
            if constexpr (MODE == 0) {  // fused transpose write: 4 consecutive s at fixed d
                int mrow0 = m0 + wm * 64 + mt * 16 + lgrp * 4;
                int b = mrow0 >> 11, s0 = mrow0 & 2047;
                int h = ncol >> 6, d = ncol & 63;
                uint2 pk; pk.x = lo; pk.y = hi;
                *(uint2*)&vtb[((size_t)(b * 16 + h) * 64 + d) * 2048 + s0] = pk;
            }
        }
        if constexpr (MODE == 0) {  // reduce 32-row chunk sums across the 4 lgrp groups
            cs0 += __shfl_xor(cs0, 16);
            cs0 += __shfl_xor(cs0, 32);
            cs1 += __shfl_xor(cs1, 16);
            cs1 += __shfl_xor(cs1, 32);
            if (lgrp == 0) {
                int b = m0 >> 11, h = ncol >> 6, d = ncol & 63;
                int bh = b * 16 + h;
                int c0 = ((m0 & 2047) >> 5) + wm * 2;
                psum[((size_t)bh * 64 + c0) * 64 + d] = cs0;
                psum[((size_t)bh * 64 + c0 + 1) * 64 + d] = cs1;
            }
        }
    }
    if constexpr (MODE == 0) {
#pragma unroll
        for (int m = 1; m < 64; m <<= 1) {
            vmin = fminf(vmin, __shfl_xor(vmin, m));
            vmax = fmaxf(vmax, __shfl_xor(vmax, m));
        }
        if (lane == 0) {
            int b = m0 >> 11;
            atomicMin(&mm[b * 2], fenc(vmin));
            atomicMax(&mm[b * 2 + 1], fenc(vmax));
        }
    }
}

// pass 2: one thread per (bh,d); register scan of 64 chunk sums -> exclusive base[bh][c][d]
__global__ __launch_bounds__(64) void k_scan2(const float* __restrict__ ps,
                                              float* __restrict__ base) {
    int bh = blockIdx.x;
    int d = threadIdx.x;
    const float* p = ps + (size_t)bh * 64 * 64 + d;
    float* bo = base + (size_t)bh * 64 * 64 + d;
    float vals[64];
#pragma unroll
    for (int c = 0; c < 64; ++c) vals[c] = p[(size_t)c * 64];
    float run = 0.f;
#pragma unroll
    for (int c = 0; c < 64; ++c) {
        float t = vals[c];
        vals[c] = run;
        run += t;
    }
#pragma unroll
    for (int c = 0; c < 64; ++c) bo[(size_t)c * 64] = vals[c];
}

// Fixed-max flash attention v6: FUSED gene computation (scan3 deleted).
// Block = 4 waves x 16 query rows = 64 rows of one bh; key tile = 64; grid 1024 longest-first,
// 4 blocks/CU. Prologue per wave: lane=d resumes the prefix scan from base[bh][i0>>5]
// (+16 pre-rows if w&1), 16-step serial scan with 6-shuffle rowsum -> gene rows [i0,i0+16)
// bf16 into plds[w] (free at this point: ga frags are read ONCE into regs before the K loop,
// then plds is reused for P^T). Same numerics as the old k_scan3 (same f2bf rounding).
// K loop unchanged: depth-1 DMA prefetch, one barrier/tile; QK swapped; cvt_pk packed P^T;
// p = exp2(s - C2) fixed shift; denom = per-lane sum + 2 shuffles.
// OUTPUT: K-blocked a_p[h][m][64] for the wo gemm.
__global__ __launch_bounds__(256, 4) void k_attn(const unsigned short* __restrict__ vb,
                                                 const unsigned short* __restrict__ vt,
                                                 unsigned short* __restrict__ attn_out,
                                                 const float* __restrict__ base,
                                                 const unsigned int* __restrict__ mm) {
    __shared__ __align__(16) unsigned short Vsm[2][4096];   // [buf][j 64][d 64] linear
    __shared__ __align__(16) unsigned short Tsm[2][4096];   // [buf][d 64][j 64] linear
    __shared__ __align__(16) unsigned short plds[4][1024];  // gene staging, then P^T [16][64]
    int tid = threadIdx.x, lane = tid & 63, w = tid >> 6;
    int bid = blockIdx.x;
    int qt = 31 - (bid >> 5);                      // 64-row q tile, longest first
    int bh = ((bid & 7) << 2) | ((bid >> 3) & 3);  // XCD-major bh
    int i0 = qt * 64 + w * 16;
    int lrow = lane & 15, lgrp = lane >> 4;
    int sx = lrow & 7;
    int r8 = lane >> 3, ch = lane & 7;

    int b = bh >> 4;
    float vmin = fdec(mm[b * 2]), vmax = fdec(mm[b * 2 + 1]);
    float ir = __fdividef(1.0f, vmax - vmin + 1e-8f);
    float C2 = (vmin * ir + 1.0f) * 1.4426950408889634f;  // fixed softmax shift, log2 domain

    const unsigned short* vbase = vb + (size_t)bh * S_ * 64;
    const unsigned short* tbase = vt + (size_t)bh * 64 * S_;

    // ---- fused scan3: gene rows [i0, i0+16) -> plds[w] (lane = d) ----
    {
        int c = i0 >> 5;  // 32-row chunk
        float acc = base[((size_t)bh * 64 + c) * 64 + lane];
        const unsigned short* vrow = vbase + (size_t)(c << 5) * 64 + lane;
        if (w & 1) {  // skip first 16 rows of the chunk
            float p0 = 0.f, p1 = 0.f, p2 = 0.f, p3 = 0.f;
#pragma unroll
            for (int r = 0; r < 16; r += 4) {
                p0 += bf2f(vrow[(size_t)r * 64]);
                p1 += bf2f(vrow[(size_t)(r + 1) * 64]);
                p2 += bf2f(vrow[(size_t)(r + 2) * 64]);
                p3 += bf2f(vrow[(size_t)(r + 3) * 64]);
            }
            acc += (p0 + p1) + (p2 + p3);
            vrow += 16 * 64;
        }
        float irl = ir * 1.4426950408889634f;
#pragma unroll 4
        for (int r = 0; r < 16; ++r) {
            acc += bf2f(vrow[(size_t)r * 64]);
            float phi = __fdividef(acc, (float)(i0 + r + 1));
            float inv = __fdividef(1.0f, (phi - vmin) * ir + 0.5f);
            float rs = inv;
#pragma unroll
            for (int m2 = 1; m2 < 64; m2 <<= 1) rs += __shfl_xor(rs, m2);
            plds[w][r * 64 + lane] = f2bf(__fdividef(inv, rs) * irl);
        }
    }
    // one-time frag read (wave-local LDS, in-order per wave); then plds is reused for P^T
    bf16x8 ga0 = *(const bf16x8*)&plds[w][lrow * 64 + lgrp * 8];
    bf16x8 ga1 = *(const bf16x8*)&plds[w][lrow * 64 + 32 + lgrp * 8];

    // DMA staging sources (pre-swizzled chunk)
    const unsigned short* Vg = vbase + (size_t)(w * 8 + r8) * 64 + ((ch ^ r8) << 3);
    const unsigned short* Tg = tbase + (size_t)(w * 8 + r8) * S_ + ((ch ^ r8) << 3);

#define ASTAGE(buf, jt_)                                                                  \
    {                                                                                     \
        int j0s = (jt_) << 6;                                                             \
        _Pragma("unroll") for (int i = 0; i < 2; ++i)                                     \
            gload16(Vg + (size_t)(j0s + i * 32) * 64, &Vsm[buf][(i * 32 + w * 8) * 64]);  \
        _Pragma("unroll") for (int i = 0; i < 2; ++i)                                     \
            gload16(Tg + (size_t)(i * 32) * S_ + j0s, &Tsm[buf][(i * 32 + w * 8) * 64]);  \
    }

    f32x4 acc[4];
#pragma unroll
    for (int dn = 0; dn < 4; ++dn) acc[dn] = (f32x4){0.f, 0.f, 0.f, 0.f};
    float lsum = 0.f;

    int njt = qt + 1;  // uniform across the block's 4 waves
    ASTAGE(0, 0);
    for (int jt = 0; jt < njt; ++jt) {
        int cur = jt & 1;
        asm volatile("s_waitcnt vmcnt(0)" ::: "memory");  // tile jt landed (issued 1 compute ago)
        __builtin_amdgcn_s_barrier();   // all waves consumed buf[(jt-1)&1] reads in iter jt-1
        __builtin_amdgcn_sched_barrier(0);
        if (jt + 1 < njt) ASTAGE(cur ^ 1, jt + 1);  // safe: that buf's reads done
        int j0 = jt << 6;
        __builtin_amdgcn_s_setprio(1);
        // ---- swapped scores: D[j=4lgrp+r][i=lrow] ----
        f32x4 Sv[4];
#pragma unroll
        for (int n = 0; n < 4; ++n) {
            const unsigned short* vr = &Vsm[cur][(n * 16 + lrow) * 64];
            bf16x8 a0 = *(const bf16x8*)(vr + ((lgrp ^ sx) << 3));
            bf16x8 a1 = *(const bf16x8*)(vr + (((lgrp + 4) ^ sx) << 3));
            f32x4 c = (f32x4){0.f, 0.f, 0.f, 0.f};
            c = mfma16(a0, ga0, c);
            c = mfma16(a1, ga1, c);
            Sv[n] = c;
        }
        bool tail = (jt == njt - 1);
        // ---- p = exp2(s - C2); per-lane denom; pack; swizzled 8B P^T writes ----
#pragma unroll
        for (int n = 0; n < 4; ++n) {
            float q0 = exp2f(Sv[n][0] - C2);
            float q1 = exp2f(Sv[n][1] - C2);
            float q2 = exp2f(Sv[n][2] - C2);
            float q3 = exp2f(Sv[n][3] - C2);
            if (tail) {
                int ii = i0 + lrow;
                int jj = j0 + n * 16 + 4 * lgrp;
                q0 = (jj     <= ii) ? q0 : 0.f;
                q1 = (jj + 1 <= ii) ? q1 : 0.f;
                q2 = (jj + 2 <= ii) ? q2 : 0.f;
                q3 = (jj + 3 <= ii) ? q3 : 0.f;
            }
            lsum += (q0 + q1) + (q2 + q3);
            uint2 pk;
            pk.x = cvt_pk_bf16(q0, q1);
            pk.y = cvt_pk_bf16(q2, q3);
            int chunk = 2 * n + (lgrp >> 1);
            *(uint2*)&plds[w][lrow * 64 + ((chunk ^ sx) << 3) + ((lgrp & 1) << 2)] = pk;
        }
        // wave-local LDS RAW: DS ops in-order per wave; compiler inserts lgkmcnt.
        // ---- PV^T: acc[dn] += T(16d x 32j) * P^T(16i x 32j) ----
#pragma unroll
        for (int chk = 0; chk < 2; ++chk) {
            int pc = ((chk * 4 + lgrp) ^ sx) << 3;
            bf16x8 pa = *(const bf16x8*)&plds[w][lrow * 64 + pc];
#pragma unroll
            for (int dn = 0; dn < 4; ++dn) {
                bf16x8 tf = *(const bf16x8*)&Tsm[cur][(dn * 16 + lrow) * 64 + pc];
                acc[dn] = mfma16(tf, pa, acc[dn]);
            }
        }
        __builtin_amdgcn_s_setprio(0);
    }
#undef ASTAGE
    // denominator: sum across the 4 lgrp groups (j-partials)
    lsum += __shfl_xor(lsum, 16);
    lsum += __shfl_xor(lsum, 32);
    lsum = __fdividef(1.0f, lsum);
    int bb = bh >> 4, h = bh & 15;
    int ii = i0 + lrow;
#pragma unroll
    for (int dn = 0; dn < 4; ++dn) {
        uint2 pk;
        pk.x = cvt_pk_bf16(acc[dn][0] * lsum, acc[dn][1] * lsum);
        pk.y = cvt_pk_bf16(acc[dn][2] * lsum, acc[dn][3] * lsum);
        // K-blocked output: a_p[kt=h][m=bb*S_+ii][64] at offset dn*16 + lgrp*4
        *(uint2*)&attn_out[((size_t)h * M_ + bb * S_ + ii) * 64 + dn * 16 + lgrp * 4] = pk;
    }
}

extern "C" void kernel_launch(void* const* d_in, const int* in_sizes, int n_in,
                              void* d_out, int out_size, void* d_ws, size_t ws_size,
                              hipStream_t stream) {
    const float* x = (const float*)d_in[0];
    const float* wv_w = (const float*)d_in[1];
    const float* wv_b = (const float*)d_in[2];
    const float* wo_w = (const float*)d_in[3];
    const float* wo_b = (const float*)d_in[4];
    float* out = (float*)d_out;

    char* w = (char*)d_ws;
    unsigned short* x_bf = (unsigned short*)(w);               // 8 MB  blocked [16][4096][64]
    unsigned short* wv_bf = (unsigned short*)(w + 8388608);    // 2 MB  blocked [16][1024][64]
    unsigned short* wo_bf = (unsigned short*)(w + 10485760);   // 2 MB  blocked [16][1024][64]
    unsigned short* v_bf = (unsigned short*)(w + 12582912);    // 8 MB  [b][h][s][d]
    unsigned short* vt_bf = (unsigned short*)(w + 20971520);   // 8 MB  [b][h][d][s]
    float* ps = (float*)(w + 29360128);                        // 512 KB [bh][c][d]
    float* base = (float*)(w + 29884416);                      // 512 KB [bh][c][d]
    unsigned short* a_bf = (unsigned short*)(w + 54525952);    // 8 MB  blocked [16][4096][64]
    unsigned int* mm = (unsigned int*)(w + 62914560);          // 16 B
    if (ws_size < 62914576) return;  // insufficient workspace -> fail loudly

    k_prep<<<3072, 256, 0, stream>>>(x, wv_w, wo_w, x_bf, wv_bf, wo_bf, mm);
    k_gemm<0><<<dim3(32, 8), 256, 0, stream>>>(x_bf, wv_bf, wv_b, v_bf, vt_bf, ps, nullptr, mm);
    k_scan2<<<32, 64, 0, stream>>>(ps, base);
    k_attn<<<1024, 256, 0, stream>>>(v_bf, vt_bf, a_bf, base, mm);
    k_gemm<1><<<dim3(32, 8), 256, 0, stream>>>(a_bf, wo_bf, wo_b, nullptr, nullptr, nullptr, out, nullptr);
}